// Round 15
// baseline (606.451 us; speedup 1.0000x reference)
//
#include <hip/hip_runtime.h>
#include <math.h>

#define S_    2048
#define DM_   4096
#define H_    32
#define KVH_  8
#define HD_   128

typedef __bf16 bf16x8 __attribute__((ext_vector_type(8)));
typedef float  f32x4  __attribute__((ext_vector_type(4)));
typedef unsigned short u16x8 __attribute__((ext_vector_type(8)));
typedef unsigned short ushort_t;

// float -> bf16 bits, round-to-nearest-even
__device__ __forceinline__ ushort_t f2b(float f) {
  unsigned int u = __float_as_uint(f);
  unsigned int r = (u + 0x7fffu + ((u >> 16) & 1u)) >> 16;
  return (ushort_t)r;
}
__device__ __forceinline__ float b2f(ushort_t h) {
  return __uint_as_float(((unsigned int)h) << 16);
}
__device__ __forceinline__ bf16x8 asbf(u16x8 v) {
  return __builtin_bit_cast(bf16x8, v);
}

// async global->LDS, 16 bytes per lane
__device__ __forceinline__ void gload16(const void* g, void* l) {
  __builtin_amdgcn_global_load_lds(
      (const __attribute__((address_space(1))) void*)g,
      (__attribute__((address_space(3))) void*)(unsigned int)(unsigned long long)l,
      16, 0, 0);
}

// ---------------- Newton inverse: X0 = 2I - A (both matrices) ----------------
__global__ void newton_init(const float* __restrict__ A0, const float* __restrict__ A1,
                            float* __restrict__ X0, float* __restrict__ X1)
{
  const float* A = blockIdx.x ? A1 : A0;
  float*       X = blockIdx.x ? X1 : X0;
  const int i = blockIdx.y * 1024 + threadIdx.x;
  const int r = i >> 7, c = i & 127;
  X[i] = ((r == c) ? 2.0f : 0.0f) - A[i];
}

// ---------------- 128x128 fp32 matmul, dual-matrix, Newton-step epilogue --------------
__global__ __launch_bounds__(256) void nmm(
    const float* __restrict__ A0, const float* __restrict__ B0, float* __restrict__ C0, int tr0,
    const float* __restrict__ A1, const float* __restrict__ B1, float* __restrict__ C1, int tr1,
    int update)
{
  const float* A = blockIdx.y ? A1 : A0;
  const float* B = blockIdx.y ? B1 : B0;
  float*       C = blockIdx.y ? C1 : C0;
  const int tr   = blockIdx.y ? tr1 : tr0;
  const int m0   = blockIdx.x * 32;
  const int tid  = threadIdx.x;

  __shared__ float Bs[128][132];
  __shared__ float As[32][132];

#pragma unroll
  for (int i = 0; i < 16; ++i) {
    int idx = tid + i * 256;
    int row = idx >> 5, c4 = (idx & 31) * 4;
    *(float4*)&Bs[row][c4] = *(const float4*)&B[row * 128 + c4];
  }
#pragma unroll
  for (int i = 0; i < 4; ++i) {
    int idx = tid + i * 256;
    int row = idx >> 5, c4 = (idx & 31) * 4;
    *(float4*)&As[row][c4] = *(const float4*)&A[(m0 + row) * 128 + c4];
  }
  __syncthreads();

  const int rloc = tid >> 3;
  const int c0   = (tid & 7) * 16;
  float acc[16];
#pragma unroll
  for (int j = 0; j < 16; ++j) acc[j] = 0.0f;
  for (int k = 0; k < 128; ++k) {
    float a = As[rloc][k];
#pragma unroll
    for (int j = 0; j < 16; j += 4) {
      float4 bv = *(const float4*)&Bs[k][c0 + j];
      acc[j + 0] += a * bv.x; acc[j + 1] += a * bv.y;
      acc[j + 2] += a * bv.z; acc[j + 3] += a * bv.w;
    }
  }
#pragma unroll
  for (int j = 0; j < 16; ++j) {
    float v = update ? (2.0f * As[rloc][c0 + j] - acc[j]) : acc[j];
    if (tr) C[(c0 + j) * 128 + (m0 + rloc)] = v;
    else    C[(m0 + rloc) * 128 + c0 + j]   = v;
  }
}

// ---------------- prep_all: fragment packs for T matrices + LN R/L -------------------
// blocks 0..3: 128x128 B-frag hi/lo for {Tkit, Tk, Tv, TvI^T(on-the-fly transpose)}
// blocks 4..5: 64x64 B-frag hi/lo for {lnR, lnL}
__global__ void prep_all(const float* __restrict__ Tkit, const float* __restrict__ Tk,
                         const float* __restrict__ Tv,   const float* __restrict__ TvI,
                         const float* __restrict__ lnR,  const float* __restrict__ lnL,
                         ushort_t* __restrict__ Fhi, ushort_t* __restrict__ Flo,
                         ushort_t* __restrict__ RBh, ushort_t* __restrict__ RBl,
                         ushort_t* __restrict__ LBh, ushort_t* __restrict__ LBl)
{
  const int mat = blockIdx.x;   // 0..5
  const int t   = threadIdx.x;  // 256
  if (mat < 4) {
    const float* src = (mat == 0) ? Tkit : ((mat == 1) ? Tk : ((mat == 2) ? Tv : TvI));
    const int tr = (mat == 3);
    ushort_t* hi = Fhi + mat * 16384;
    ushort_t* lo = Flo + mat * 16384;
    for (int ch = 0; ch < 32; ++ch) {
      int nt = ch >> 2, ds = ch & 3;
#pragma unroll
      for (int i = 0; i < 2; ++i) {
        int idx = t + i * 256;            // 0..511
        int ln = idx >> 3, j = idx & 7;
        int cc = ln & 15, gg = ln >> 4;
        int d = ds * 32 + gg * 8 + j, n = nt * 16 + cc;
        float x = tr ? src[n * 128 + d] : src[d * 128 + n];
        ushort_t hb = f2b(x);
        hi[(ch << 9) + idx] = hb;
        lo[(ch << 9) + idx] = f2b(x - b2f(hb));
      }
    }
  } else {
    const float* src = (mat == 4) ? lnR : lnL;
    ushort_t* hp = (mat == 4) ? RBh : LBh;
    ushort_t* lp = (mat == 4) ? RBl : LBl;
    for (int ch = 0; ch < 8; ++ch) {
      int nt = ch >> 1, ds = ch & 1;
#pragma unroll
      for (int i = 0; i < 2; ++i) {
        int idx = t + i * 256;
        int ln = idx >> 3, j = idx & 7;
        int cc = ln & 15, gg = ln >> 4;
        float x = src[(ds * 32 + gg * 8 + j) * 64 + nt * 16 + cc];
        ushort_t hb = f2b(x);
        hp[(ch << 9) + idx] = hb;
        lp[(ch << 9) + idx] = f2b(x - b2f(hb));
      }
    }
  }
}

// ---------------- RoPE cos/sin table: exactly numpy fp32 math ----------------
__global__ void rope_table(const int* __restrict__ pos,
                           float* __restrict__ cosT, float* __restrict__ sinT)
{
  const int s = blockIdx.x, i = threadIdx.x;
  float invf = 1.0f / (float)pow(10000.0, (double)i * (1.0 / 64.0));
  float ang  = (float)pos[s] * invf;
  cosT[s * 64 + i] = cosf(ang);
  sinT[s * 64 + i] = sinf(ang);
}

// ---------------- ln3: bilinear LN via hi/lo 3-pass MFMA ----------------
__global__ __launch_bounds__(256) void ln3(
    const float* __restrict__ hid,
    const ushort_t* __restrict__ RBh, const ushort_t* __restrict__ RBl,
    const ushort_t* __restrict__ LBh, const ushort_t* __restrict__ LBl,
    ushort_t* __restrict__ hb16, ushort_t* __restrict__ hlo16)
{
  const int blk = blockIdx.x;     // 512
  const int tid = threadIdx.x;
  const int w = tid >> 6, lane = tid & 63;
  const int c = lane & 15, g = lane >> 4;

  __shared__ float Hs[4][64 * 68];

#pragma unroll
  for (int i = 0; i < 16; ++i) {
    int idx = tid + i * 256;
    int t = idx >> 10, e = idx & 1023;
    int l = e >> 4, r4 = (e & 15) * 4;
    *(float4*)&Hs[t][l * 68 + r4] =
        *(const float4*)&hid[((size_t)(blk * 4 + t)) * 4096 + l * 64 + r4];
  }
  __syncthreads();

  float* Hw = Hs[w];

  u16x8 ah[4][2], al[4][2];
#pragma unroll
  for (int mt = 0; mt < 4; ++mt)
#pragma unroll
    for (int ds = 0; ds < 2; ++ds) {
      u16x8 th, tl;
#pragma unroll
      for (int j = 0; j < 8; ++j) {
        float x = Hw[(mt * 16 + c) * 68 + ds * 32 + g * 8 + j];
        ushort_t hb = f2b(x); th[j] = hb; tl[j] = f2b(x - b2f(hb));
      }
      ah[mt][ds] = th; al[mt][ds] = tl;
    }

  f32x4 acc[4][4];
#pragma unroll
  for (int mt = 0; mt < 4; ++mt)
#pragma unroll
    for (int nt = 0; nt < 4; ++nt) acc[mt][nt] = (f32x4){0.f, 0.f, 0.f, 0.f};
#pragma unroll
  for (int nt = 0; nt < 4; ++nt) {
    u16x8 bh[2], bl[2];
#pragma unroll
    for (int ds = 0; ds < 2; ++ds) {
      bh[ds] = *(const u16x8*)(RBh + ((nt * 2 + ds) << 9) + lane * 8);
      bl[ds] = *(const u16x8*)(RBl + ((nt * 2 + ds) << 9) + lane * 8);
    }
#pragma unroll
    for (int mt = 0; mt < 4; ++mt)
#pragma unroll
      for (int ds = 0; ds < 2; ++ds) {
        acc[mt][nt] = __builtin_amdgcn_mfma_f32_16x16x32_bf16(asbf(ah[mt][ds]), asbf(bh[ds]), acc[mt][nt], 0, 0, 0);
        acc[mt][nt] = __builtin_amdgcn_mfma_f32_16x16x32_bf16(asbf(ah[mt][ds]), asbf(bl[ds]), acc[mt][nt], 0, 0, 0);
        acc[mt][nt] = __builtin_amdgcn_mfma_f32_16x16x32_bf16(asbf(al[mt][ds]), asbf(bh[ds]), acc[mt][nt], 0, 0, 0);
      }
  }

#pragma unroll
  for (int mt = 0; mt < 4; ++mt)
#pragma unroll
    for (int nt = 0; nt < 4; ++nt)
#pragma unroll
      for (int reg = 0; reg < 4; ++reg)
        Hw[(mt * 16 + g * 4 + reg) * 68 + nt * 16 + c] = acc[mt][nt][reg];

  u16x8 a2h[4][2], a2l[4][2];
#pragma unroll
  for (int mt = 0; mt < 4; ++mt)
#pragma unroll
    for (int ds = 0; ds < 2; ++ds) {
      a2h[mt][ds] = *(const u16x8*)(LBh + ((mt * 2 + ds) << 9) + lane * 8);
      a2l[mt][ds] = *(const u16x8*)(LBl + ((mt * 2 + ds) << 9) + lane * 8);
    }
  f32x4 acc2[4][4];
#pragma unroll
  for (int mt = 0; mt < 4; ++mt)
#pragma unroll
    for (int nt = 0; nt < 4; ++nt) acc2[mt][nt] = (f32x4){0.f, 0.f, 0.f, 0.f};
#pragma unroll
  for (int nt = 0; nt < 4; ++nt) {
#pragma unroll
    for (int ds = 0; ds < 2; ++ds) {
      u16x8 bh, bl;
#pragma unroll
      for (int j = 0; j < 8; ++j) {
        float x = Hw[(ds * 32 + g * 8 + j) * 68 + nt * 16 + c];
        ushort_t hb = f2b(x); bh[j] = hb; bl[j] = f2b(x - b2f(hb));
      }
#pragma unroll
      for (int mt = 0; mt < 4; ++mt) {
        acc2[mt][nt] = __builtin_amdgcn_mfma_f32_16x16x32_bf16(asbf(a2h[mt][ds]), asbf(bh), acc2[mt][nt], 0, 0, 0);
        acc2[mt][nt] = __builtin_amdgcn_mfma_f32_16x16x32_bf16(asbf(a2h[mt][ds]), asbf(bl), acc2[mt][nt], 0, 0, 0);
        acc2[mt][nt] = __builtin_amdgcn_mfma_f32_16x16x32_bf16(asbf(a2l[mt][ds]), asbf(bh), acc2[mt][nt], 0, 0, 0);
      }
    }
  }

  ushort_t* hp = (ushort_t*)Hw;       // hi plane [64][64]; lo plane at +4096
#pragma unroll
  for (int mt = 0; mt < 4; ++mt)
#pragma unroll
    for (int nt = 0; nt < 4; ++nt)
#pragma unroll
      for (int reg = 0; reg < 4; ++reg) {
        int a = mt * 16 + g * 4 + reg, cc2 = nt * 16 + c;
        float v = acc2[mt][nt][reg];
        ushort_t hb = f2b(v);
        hp[a * 64 + cc2] = hb;
        hp[4096 + a * 64 + cc2] = f2b(v - b2f(hb));
      }

  const size_t sbase = ((size_t)(blk * 4 + w)) * 4096;
#pragma unroll
  for (int i = 0; i < 8; ++i) {
    int idx = i * 64 + lane;
    int row = idx >> 3, c8 = (idx & 7) * 8;
    *(u16x8*)&hb16[sbase + row * 64 + c8]  = *(const u16x8*)&hp[row * 64 + c8];
    *(u16x8*)&hlo16[sbase + row * 64 + c8] = *(const u16x8*)&hp[4096 + row * 64 + c8];
  }
}

// ---------------- weight transpose + bf16 cast (hi only): W[K][N] -> WT[N][K] ----------
__global__ void wtrans(const float* __restrict__ W, ushort_t* __restrict__ WT,
                       int K, int N)
{
  __shared__ ushort_t t[64][68];
  const int tid = threadIdx.x;
  const int n0 = blockIdx.x * 64, k0 = blockIdx.y * 64;
  for (int idx = tid; idx < 4096; idx += 256) {
    int rr = idx >> 6, cc = idx & 63;
    t[cc][rr] = f2b(W[(size_t)(k0 + rr) * N + n0 + cc]);
  }
  __syncthreads();
  for (int idx = tid; idx < 4096; idx += 256) {
    int rr = idx >> 6, cc = idx & 63;
    WT[(size_t)(n0 + rr) * K + k0 + cc] = t[rr][cc];
  }
}

// ---------------- weight transpose + hi/lo split, z selects Wk(0)/Wv(1) --------------
__global__ void wtrans_hl2(const float* __restrict__ Wk, const float* __restrict__ Wv,
                           ushort_t* __restrict__ WThi, ushort_t* __restrict__ WTlo)
{
  const int which = blockIdx.z;
  const float* W = which ? Wv : Wk;
  const int rowoff = which ? 1024 : 0;
  const int K = DM_, N = 1024;
  __shared__ ushort_t th[64][68];
  __shared__ ushort_t tl[64][68];
  const int tid = threadIdx.x;
  const int n0 = blockIdx.x * 64, k0 = blockIdx.y * 64;
  for (int idx = tid; idx < 4096; idx += 256) {
    int rr = idx >> 6, cc = idx & 63;
    float x = W[(size_t)(k0 + rr) * N + n0 + cc];
    ushort_t h = f2b(x);
    th[cc][rr] = h;
    tl[cc][rr] = f2b(x - b2f(h));
  }
  __syncthreads();
  for (int idx = tid; idx < 4096; idx += 256) {
    int rr = idx >> 6, cc = idx & 63;
    size_t o = (size_t)(rowoff + n0 + rr) * K + k0 + cc;
    WThi[o] = th[rr][cc];
    WTlo[o] = tl[rr][cc];
  }
}

// ---------------- wfold3: MFMA hi/lo 3-pass fold of TvI into Wo ----------------
__global__ __launch_bounds__(256) void wfold3(
    const float* __restrict__ Wo,
    const ushort_t* __restrict__ TBh, const ushort_t* __restrict__ TBl,
    ushort_t* __restrict__ WT)
{
  const int n0 = blockIdx.x * 128;
  const int h  = blockIdx.y;
  const int tid = threadIdx.x;
  const int w = tid >> 6, lane = tid & 63;
  const int c = lane & 15, g = lane >> 4;

  __shared__ float WoS[128 * 132];

#pragma unroll
  for (int i = 0; i < 16; ++i) {
    int idx = tid + i * 256;
    int e = idx >> 5, n4 = (idx & 31) * 4;
    *(float4*)&WoS[e * 132 + n4] =
        *(const float4*)&Wo[(size_t)(h * 128 + e) * 4096 + n0 + n4];
  }
  __syncthreads();

  u16x8 ah[2][4], al[2][4];
#pragma unroll
  for (int mt = 0; mt < 2; ++mt)
#pragma unroll
    for (int ds = 0; ds < 4; ++ds) {
      u16x8 th, tl;
#pragma unroll
      for (int j = 0; j < 8; ++j) {
        float x = WoS[(ds * 32 + g * 8 + j) * 132 + w * 32 + mt * 16 + c];
        ushort_t hb = f2b(x); th[j] = hb; tl[j] = f2b(x - b2f(hb));
      }
      ah[mt][ds] = th; al[mt][ds] = tl;
    }

  f32x4 acc[2][8];
#pragma unroll
  for (int mt = 0; mt < 2; ++mt)
#pragma unroll
    for (int nt = 0; nt < 8; ++nt) acc[mt][nt] = (f32x4){0.f, 0.f, 0.f, 0.f};
#pragma unroll
  for (int nt = 0; nt < 8; ++nt) {
#pragma unroll
    for (int ds = 0; ds < 4; ++ds) {
      u16x8 bh = *(const u16x8*)(TBh + ((nt * 4 + ds) << 9) + lane * 8);
      u16x8 bl = *(const u16x8*)(TBl + ((nt * 4 + ds) << 9) + lane * 8);
#pragma unroll
      for (int mt = 0; mt < 2; ++mt) {
        acc[mt][nt] = __builtin_amdgcn_mfma_f32_16x16x32_bf16(asbf(ah[mt][ds]), asbf(bh), acc[mt][nt], 0, 0, 0);
        acc[mt][nt] = __builtin_amdgcn_mfma_f32_16x16x32_bf16(asbf(ah[mt][ds]), asbf(bl), acc[mt][nt], 0, 0, 0);
        acc[mt][nt] = __builtin_amdgcn_mfma_f32_16x16x32_bf16(asbf(al[mt][ds]), asbf(bh), acc[mt][nt], 0, 0, 0);
      }
    }
  }
  __syncthreads();

  ushort_t* OS = (ushort_t*)WoS;
#pragma unroll
  for (int mt = 0; mt < 2; ++mt)
#pragma unroll
    for (int nt = 0; nt < 8; ++nt)
#pragma unroll
      for (int reg = 0; reg < 4; ++reg)
        OS[(w * 32 + mt * 16 + g * 4 + reg) * 136 + nt * 16 + c] = f2b(acc[mt][nt][reg]);
  __syncthreads();

#pragma unroll
  for (int i = 0; i < 8; ++i) {
    int idx = tid + i * 256;
    int nn = idx >> 4, c8 = (idx & 15) * 8;
    *(u16x8*)&WT[(size_t)(n0 + nn) * 4096 + h * 128 + c8] = *(const u16x8*)&OS[nn * 136 + c8];
  }
}

// ---------------- bf16 MFMA GEMM (m97 structure): C = A x BT^T ----------------
__global__ __launch_bounds__(256) void gemm_bf16(const ushort_t* __restrict__ A,
                                                 const ushort_t* __restrict__ BT,
                                                 float* __restrict__ C,
                                                 int M, int N, int K, int qlayout)
{
  __shared__ __align__(16) ushort_t As[128 * 64];
  __shared__ __align__(16) ushort_t Bs[128 * 64];
  const int tid = threadIdx.x;
  const int bm = blockIdx.y * 128, bn = blockIdx.x * 128;
  const int lane = tid & 63, w = tid >> 6;
  const int c = lane & 15, g = lane >> 4;
  const int wm = (w >> 1) * 64, wn = (w & 1) * 64;
  f32x4 acc[4][4];
#pragma unroll
  for (int mt = 0; mt < 4; ++mt)
#pragma unroll
    for (int nt = 0; nt < 4; ++nt) acc[mt][nt] = (f32x4){0.f, 0.f, 0.f, 0.f};
  const int srow = tid >> 3;
  const int slot = (tid & 7) ^ (srow & 7);
  for (int k0 = 0; k0 < K; k0 += 64) {
    __syncthreads();
#pragma unroll
    for (int ii = 0; ii < 4; ++ii) {
      gload16(A  + (size_t)(bm + ii * 32 + srow) * K + k0 + slot * 8,
              (char*)As + w * 1024 + ii * 4096);
      gload16(BT + (size_t)(bn + ii * 32 + srow) * K + k0 + slot * 8,
              (char*)Bs + w * 1024 + ii * 4096);
    }
    __syncthreads();
#pragma unroll
    for (int ks = 0; ks < 2; ++ks) {
      bf16x8 av[4], bv[4];
#pragma unroll
      for (int mt = 0; mt < 4; ++mt)
        av[mt] = *(const bf16x8*)((const char*)As + (wm + mt * 16 + c) * 128 +
                                  (((ks * 4 + g) ^ (c & 7)) << 4));
#pragma unroll
      for (int nt = 0; nt < 4; ++nt)
        bv[nt] = *(const bf16x8*)((const char*)Bs + (wn + nt * 16 + c) * 128 +
                                  (((ks * 4 + g) ^ (c & 7)) << 4));
#pragma unroll
      for (int mt = 0; mt < 4; ++mt)
#pragma unroll
        for (int nt = 0; nt < 4; ++nt)
          acc[mt][nt] = __builtin_amdgcn_mfma_f32_16x16x32_bf16(av[mt], bv[nt], acc[mt][nt], 0, 0, 0);
    }
  }
#pragma unroll
  for (int mt = 0; mt < 4; ++mt)
#pragma unroll
    for (int nt = 0; nt < 4; ++nt)
#pragma unroll
      for (int reg = 0; reg < 4; ++reg) {
        int m = bm + wm + mt * 16 + g * 4 + reg;
        int n = bn + wn + nt * 16 + c;
        float v = acc[mt][nt][reg];
        if (qlayout) C[((size_t)(n >> 7) * S_ + m) * 128 + (n & 127)] = v;
        else         C[(size_t)m * N + n] = v;
      }
}

// ---------------- 3-pass split-bf16 MFMA GEMM (near-fp32); out [kvh][s][d] ------------
__global__ __launch_bounds__(256) void gemm_bf16_3(
    const ushort_t* __restrict__ Ahi, const ushort_t* __restrict__ Alo,
    const ushort_t* __restrict__ BThi, const ushort_t* __restrict__ BTlo,
    float* __restrict__ Ck, float* __restrict__ Cv, int M, int N, int K)
{
  __shared__ __align__(16) ushort_t Ash[128 * 64];
  __shared__ __align__(16) ushort_t Asl[128 * 64];
  __shared__ __align__(16) ushort_t Bsh[64 * 64];
  __shared__ __align__(16) ushort_t Bsl[64 * 64];
  const int tid = threadIdx.x;
  const int bm = blockIdx.y * 128, bn = blockIdx.x * 64;
  const int lane = tid & 63, w = tid >> 6;
  const int c = lane & 15, g = lane >> 4;
  const int wm = w * 32;
  f32x4 acc[2][4];
#pragma unroll
  for (int mt = 0; mt < 2; ++mt)
#pragma unroll
    for (int nt = 0; nt < 4; ++nt) acc[mt][nt] = (f32x4){0.f, 0.f, 0.f, 0.f};
  const int srow = tid >> 3;
  const int slot = (tid & 7) ^ (srow & 7);
  for (int k0 = 0; k0 < K; k0 += 64) {
    __syncthreads();
#pragma unroll
    for (int ii = 0; ii < 4; ++ii) {
      const size_t ga = (size_t)(bm + ii * 32 + srow) * K + k0 + slot * 8;
      gload16(Ahi + ga, (char*)Ash + w * 1024 + ii * 4096);
      gload16(Alo + ga, (char*)Asl + w * 1024 + ii * 4096);
    }
#pragma unroll
    for (int ii = 0; ii < 2; ++ii) {
      const size_t gb = (size_t)(bn + ii * 32 + srow) * K + k0 + slot * 8;
      gload16(BThi + gb, (char*)Bsh + w * 1024 + ii * 4096);
      gload16(BTlo + gb, (char*)Bsl + w * 1024 + ii * 4096);
    }
    __syncthreads();
#pragma unroll
    for (int ks = 0; ks < 2; ++ks) {
      bf16x8 ah[2], al[2], bh[4], bl[4];
#pragma unroll
      for (int mt = 0; mt < 2; ++mt) {
        int ro = (wm + mt * 16 + c) * 128;
        int so = ((ks * 4 + g) ^ (c & 7)) << 4;
        ah[mt] = *(const bf16x8*)((const char*)Ash + ro + so);
        al[mt] = *(const bf16x8*)((const char*)Asl + ro + so);
      }
#pragma unroll
      for (int nt = 0; nt < 4; ++nt) {
        int ro = (nt * 16 + c) * 128;
        int so = ((ks * 4 + g) ^ (c & 7)) << 4;
        bh[nt] = *(const bf16x8*)((const char*)Bsh + ro + so);
        bl[nt] = *(const bf16x8*)((const char*)Bsl + ro + so);
      }
#pragma unroll
      for (int mt = 0; mt < 2; ++mt)
#pragma unroll
        for (int nt = 0; nt < 4; ++nt) {
          acc[mt][nt] = __builtin_amdgcn_mfma_f32_16x16x32_bf16(ah[mt], bh[nt], acc[mt][nt], 0, 0, 0);
          acc[mt][nt] = __builtin_amdgcn_mfma_f32_16x16x32_bf16(ah[mt], bl[nt], acc[mt][nt], 0, 0, 0);
          acc[mt][nt] = __builtin_amdgcn_mfma_f32_16x16x32_bf16(al[mt], bh[nt], acc[mt][nt], 0, 0, 0);
        }
    }
  }
#pragma unroll
  for (int mt = 0; mt < 2; ++mt)
#pragma unroll
    for (int nt = 0; nt < 4; ++nt)
#pragma unroll
      for (int reg = 0; reg < 4; ++reg) {
        int m = bm + wm + mt * 16 + g * 4 + reg;
        int n = bn + nt * 16 + c;
        float v = acc[mt][nt][reg];
        if (n < 1024) Ck[((size_t)(n >> 7) * S_ + m) * 128 + (n & 127)] = v;
        else          Cv[((size_t)((n - 1024) >> 7) * S_ + m) * 128 + (n & 127)] = v;
      }
}

// ---------------- tpost_all: merged q/k/v post (rope + @T + scale/quant + frag store) --
__global__ __launch_bounds__(256) void tpost_all(
    const float* __restrict__ qsrc, const float* __restrict__ ksrc,
    const float* __restrict__ vsrc,
    const ushort_t* __restrict__ tfH, const ushort_t* __restrict__ tfL,
    const float* __restrict__ cosT, const float* __restrict__ sinT,
    ushort_t* __restrict__ qfrag, ushort_t* __restrict__ kfrag,
    ushort_t* __restrict__ vfrag)
{
  const int b = blockIdx.x;        // 0..3071
  const float* src; const ushort_t *Thi, *Tlo; ushort_t* outp; int mode, blk;
  if (b < 2048)      { src = qsrc; Thi = tfH;             Tlo = tfL;             outp = qfrag; mode = 0; blk = b; }
  else if (b < 2560) { src = ksrc; Thi = tfH + 16384;     Tlo = tfL + 16384;     outp = kfrag; mode = 1; blk = b - 2048; }
  else               { src = vsrc; Thi = tfH + 2 * 16384; Tlo = tfL + 2 * 16384; outp = vfrag; mode = 2; blk = b - 2560; }

  const int tid = threadIdx.x;
  const int w = tid >> 6, lane = tid & 63;
  const int c = lane & 15, g = lane >> 4;

  __shared__ float raw_[32 * 132];
  __shared__ float rop_[32 * 132];
  __shared__ __align__(16) ushort_t vtile[32][136];

#pragma unroll
  for (int i = 0; i < 4; ++i) {
    int idx = tid + i * 256;
    int row = idx >> 5, c4 = (idx & 31) * 4;
    *(float4*)&raw_[row * 132 + c4] =
        *(const float4*)&src[(size_t)(blk * 32 + row) * 128 + c4];
  }
  __syncthreads();

  {
    const int r = tid >> 3, co = (tid & 7) * 16;
    if (mode <= 1) {
      const int s = (blk & 63) * 32 + r;
      const float* ct = cosT + (size_t)s * 64;
      const float* st = sinT + (size_t)s * 64;
#pragma unroll
      for (int j = 0; j < 16; ++j) {
        int cc = co + j, i2 = cc & 63;
        float x = raw_[r * 132 + cc];
        float other = (cc < 64) ? raw_[r * 132 + cc + 64] : raw_[r * 132 + cc - 64];
        rop_[r * 132 + cc] = (cc < 64) ? (x * ct[i2] - other * st[i2])
                                       : (x * ct[i2] + other * st[i2]);
      }
    } else {
#pragma unroll
      for (int j = 0; j < 16; ++j) {
        int cc = co + j;
        rop_[r * 132 + cc] = raw_[r * 132 + cc];
      }
    }
  }
  __syncthreads();

  u16x8 ahu[2][4], alu[2][4];
#pragma unroll
  for (int mt = 0; mt < 2; ++mt)
#pragma unroll
    for (int ds = 0; ds < 4; ++ds) {
      u16x8 th, tl;
#pragma unroll
      for (int j = 0; j < 8; ++j) {
        float x = rop_[(mt * 16 + c) * 132 + ds * 32 + g * 8 + j];
        ushort_t hb = f2b(x);
        th[j] = hb;
        tl[j] = f2b(x - b2f(hb));
      }
      ahu[mt][ds] = th;
      alu[mt][ds] = tl;
    }

  f32x4 acc[2][2];
#pragma unroll
  for (int mt = 0; mt < 2; ++mt)
#pragma unroll
    for (int nl = 0; nl < 2; ++nl) acc[mt][nl] = (f32x4){0.f, 0.f, 0.f, 0.f};
#pragma unroll
  for (int nl = 0; nl < 2; ++nl) {
    const int nt = w * 2 + nl;
    u16x8 bh[4], bl[4];
#pragma unroll
    for (int ds = 0; ds < 4; ++ds) {
      bh[ds] = *(const u16x8*)(Thi + ((nt * 4 + ds) << 9) + lane * 8);
      bl[ds] = *(const u16x8*)(Tlo + ((nt * 4 + ds) << 9) + lane * 8);
    }
#pragma unroll
    for (int mt = 0; mt < 2; ++mt)
#pragma unroll
      for (int ds = 0; ds < 4; ++ds) {
        acc[mt][nl] = __builtin_amdgcn_mfma_f32_16x16x32_bf16(asbf(ahu[mt][ds]), asbf(bh[ds]), acc[mt][nl], 0, 0, 0);
        acc[mt][nl] = __builtin_amdgcn_mfma_f32_16x16x32_bf16(asbf(ahu[mt][ds]), asbf(bl[ds]), acc[mt][nl], 0, 0, 0);
        acc[mt][nl] = __builtin_amdgcn_mfma_f32_16x16x32_bf16(asbf(alu[mt][ds]), asbf(bh[ds]), acc[mt][nl], 0, 0, 0);
      }
  }
  __syncthreads();

#pragma unroll
  for (int mt = 0; mt < 2; ++mt)
#pragma unroll
    for (int nl = 0; nl < 2; ++nl)
#pragma unroll
      for (int reg = 0; reg < 4; ++reg)
        raw_[(mt * 16 + g * 4 + reg) * 132 + (w * 2 + nl) * 16 + c] = acc[mt][nl][reg];
  __syncthreads();

  const int r = tid >> 3, co = (tid & 7) * 16;
  float vals[16];
#pragma unroll
  for (int j = 0; j < 16; ++j) vals[j] = raw_[r * 132 + co + j];

  if (mode == 0) {
#pragma unroll
    for (int j = 0; j < 16; ++j) vals[j] *= 0.08838834764831845f;
  } else {
    float m = 0.0f;
#pragma unroll
    for (int j = 0; j < 16; ++j) m = fmaxf(m, fabsf(vals[j]));
    m = fmaxf(m, __shfl_xor(m, 1));
    m = fmaxf(m, __shfl_xor(m, 2));
    m = fmaxf(m, __shfl_xor(m, 4));
    const float sc = fmaxf(m * (1.0f / 7.0f), 1e-8f);
#pragma unroll
    for (int j = 0; j < 16; ++j) {
      float qv = rintf(vals[j] / sc);
      qv = fminf(7.0f, fmaxf(-7.0f, qv));
      vals[j] = qv * sc;
    }
  }

  if (mode <= 1) {
    const size_t chunkbase = ((size_t)blk << 13) +
                             ((size_t)((r >> 4) * 4 + (co >> 5)) << 10);
    const int lane0 = ((co >> 3) & 3) * 16 + (r & 15);
    const int lane1 = (((co + 8) >> 3) & 3) * 16 + (r & 15);
    u16x8 o0, o1;
#pragma unroll
    for (int j = 0; j < 8; ++j) { o0[j] = f2b(vals[j]); o1[j] = f2b(vals[j + 8]); }
    *(u16x8*)((char*)outp + chunkbase + lane0 * 16) = o0;
    *(u16x8*)((char*)outp + chunkbase + lane1 * 16) = o1;
  } else {
#pragma unroll
    for (int j = 0; j < 16; ++j) vtile[r][co + j] = f2b(vals[j]);
    __syncthreads();
#pragma unroll
    for (int i = 0; i < 2; ++i) {
      int id = tid + i * 256;
      int dt = id >> 6, ln = id & 63;
      int gg = ln >> 4, cc = ln & 15;
      u16x8 o;
#pragma unroll
      for (int j = 0; j < 8; ++j) o[j] = vtile[gg * 8 + j][dt * 16 + cc];
      *(u16x8*)(outp + (((size_t)blk) << 12) + (dt << 9) + ln * 8) = o;
    }
  }
}

// ---------------- MFMA flash attention v7: fixed-max softmax + 1-deep K/V register
// prefetch + hardware bf16 cvt for P. Balanced qt mapping, XCD-localized. -------------
__global__ __launch_bounds__(256) void attn_mfma7(
    const ushort_t* __restrict__ qf_,
    const ushort_t* __restrict__ kf_,
    const ushort_t* __restrict__ vf_,
    ushort_t* __restrict__ o16)
{
  const int lid = blockIdx.x;
  const int xcd = lid & 7;
  const int idx = lid >> 3;
  const int h   = xcd * 4 + (idx & 3);
  const int kb  = idx >> 2;
  const int kvh = xcd;

  const int tid = threadIdx.x;
  const int w    = tid >> 6;
  const int lane = tid & 63;
  const int c = lane & 15, g = lane >> 4;
  const int qt = (w < 2) ? (2 * kb + w) : (60 - 2 * kb + w);

  __shared__ __align__(16) ushort_t Ps[4][2][16][40];

  const float LOG2E = 1.44269504f;
  const float MBIAS = 28.8539008f;    // p = 2^(s*log2e - MBIAS) = e^(s-20)

  const char* qtile = (const char*)qf_ + (((size_t)(h * 64 + qt)) << 13);
  bf16x8 qf[2][4];
#pragma unroll
  for (int mt = 0; mt < 2; ++mt)
#pragma unroll
    for (int ds = 0; ds < 4; ++ds)
      qf[mt][ds] = *(const bf16x8*)(qtile + ((mt * 4 + ds) << 10) + lane * 16);

  bf16x8 ones;
#pragma unroll
  for (int j = 0; j < 8; ++j) ones[j] = (__bf16)1.0f;

  f32x4 oa[2][8];
#pragma unroll
  for (int mt = 0; mt < 2; ++mt)
#pragma unroll
    for (int dt = 0; dt < 8; ++dt) oa[mt][dt] = (f32x4){0.f, 0.f, 0.f, 0.f};
  f32x4 la[2];
  la[0] = (f32x4){0.f, 0.f, 0.f, 0.f};
  la[1] = (f32x4){0.f, 0.f, 0.f, 0.f};

  const char* kbase = (const char*)kf_ + (((size_t)kvh * 64) << 13);
  const char* vbase = (const char*)vf_ + (((size_t)kvh * 64) << 13);

  // prologue: load tile kt=0 (qt >= 0 always)
  bf16x8 kc[2][4], vc[8], kn[2][4], vn[8];
#pragma unroll
  for (int nt = 0; nt < 2; ++nt)
#pragma unroll
    for (int ds = 0; ds < 4; ++ds)
      kc[nt][ds] = *(const bf16x8*)(kbase + ((nt * 4 + ds) << 10) + lane * 16);
#pragma unroll
  for (int dt = 0; dt < 8; ++dt)
    vc[dt] = *(const bf16x8*)(vbase + (dt << 10) + lane * 16);

  for (int kt = 0; kt <= qt; ++kt) {
    const int ktn = kt + 1;
    if (ktn <= qt) {    // prefetch next tile into named regs; wait lands next iter
      const char* ktile = kbase + ((size_t)ktn << 13);
      const char* vtile = vbase + ((size_t)ktn << 13);
#pragma unroll
      for (int nt = 0; nt < 2; ++nt)
#pragma unroll
        for (int ds = 0; ds < 4; ++ds)
          kn[nt][ds] = *(const bf16x8*)(ktile + ((nt * 4 + ds) << 10) + lane * 16);
#pragma unroll
      for (int dt = 0; dt < 8; ++dt)
        vn[dt] = *(const bf16x8*)(vtile + (dt << 10) + lane * 16);
    }

    f32x4 sc[2][2];
#pragma unroll
    for (int mt = 0; mt < 2; ++mt)
#pragma unroll
      for (int nt = 0; nt < 2; ++nt) sc[mt][nt] = (f32x4){0.f, 0.f, 0.f, 0.f};
    __builtin_amdgcn_s_setprio(1);
#pragma unroll
    for (int ds = 0; ds < 4; ++ds) {
      sc[0][0] = __builtin_amdgcn_mfma_f32_16x16x32_bf16(qf[0][ds], kc[0][ds], sc[0][0], 0, 0, 0);
      sc[0][1] = __builtin_amdgcn_mfma_f32_16x16x32_bf16(qf[0][ds], kc[1][ds], sc[0][1], 0, 0, 0);
      sc[1][0] = __builtin_amdgcn_mfma_f32_16x16x32_bf16(qf[1][ds], kc[0][ds], sc[1][0], 0, 0, 0);
      sc[1][1] = __builtin_amdgcn_mfma_f32_16x16x32_bf16(qf[1][ds], kc[1][ds], sc[1][1], 0, 0, 0);
    }
    __builtin_amdgcn_s_setprio(0);

    // fixed-max softmax: p = e^(s-20); masked -> 0. HW RTNE cvt to bf16.
#pragma unroll
    for (int mt = 0; mt < 2; ++mt) {
#pragma unroll
      for (int reg = 0; reg < 4; ++reg) {
        float s0 = sc[mt][0][reg], s1 = sc[mt][1][reg];
        if (kt == qt) {
          int qrl = mt * 16 + g * 4 + reg;
          if (c > qrl)      s0 = -INFINITY;
          if (16 + c > qrl) s1 = -INFINITY;
        }
        float p0 = exp2f(s0 * LOG2E - MBIAS);
        float p1 = exp2f(s1 * LOG2E - MBIAS);
        Ps[w][mt][g * 4 + reg][c]      = __builtin_bit_cast(ushort_t, (__bf16)p0);
        Ps[w][mt][g * 4 + reg][16 + c] = __builtin_bit_cast(ushort_t, (__bf16)p1);
      }
    }

    bf16x8 pa0 = *reinterpret_cast<const bf16x8*>(&Ps[w][0][c][g * 8]);
    bf16x8 pa1 = *reinterpret_cast<const bf16x8*>(&Ps[w][1][c][g * 8]);
    __builtin_amdgcn_s_setprio(1);
#pragma unroll
    for (int dt = 0; dt < 8; ++dt) {
      oa[0][dt] = __builtin_amdgcn_mfma_f32_16x16x32_bf16(pa0, vc[dt], oa[0][dt], 0, 0, 0);
      oa[1][dt] = __builtin_amdgcn_mfma_f32_16x16x32_bf16(pa1, vc[dt], oa[1][dt], 0, 0, 0);
    }
    la[0] = __builtin_amdgcn_mfma_f32_16x16x32_bf16(pa0, ones, la[0], 0, 0, 0);
    la[1] = __builtin_amdgcn_mfma_f32_16x16x32_bf16(pa1, ones, la[1], 0, 0, 0);
    __builtin_amdgcn_s_setprio(0);

    if (ktn <= qt) {
#pragma unroll
      for (int nt = 0; nt < 2; ++nt)
#pragma unroll
        for (int ds = 0; ds < 4; ++ds)
          kc[nt][ds] = kn[nt][ds];
#pragma unroll
      for (int dt = 0; dt < 8; ++dt)
        vc[dt] = vn[dt];
    }
  }

#pragma unroll
  for (int mt = 0; mt < 2; ++mt)
#pragma unroll
    for (int reg = 0; reg < 4; ++reg) {
      float li = 1.0f / la[mt][reg];
      int srow = qt * 32 + mt * 16 + g * 4 + reg;
      ushort_t* orow = o16 + (size_t)srow * DM_ + h * 128;
#pragma unroll
      for (int dt = 0; dt < 8; ++dt)
        orow[dt * 16 + c] = f2b(oa[mt][dt][reg] * li);
    }
}

extern "C" void kernel_launch(void* const* d_in, const int* in_sizes, int n_in,
                              void* d_out, int out_size, void* d_ws, size_t ws_size,
                              hipStream_t stream)
{
  (void)in_sizes; (void)n_in; (void)out_size; (void)ws_size;
  const float* hidden = (const float*)d_in[0];
  const int*   pos    = (const int*)d_in[2];
  const float* lnL    = (const float*)d_in[3];
  const float* lnR    = (const float*)d_in[4];
  const float* Wq     = (const float*)d_in[5];
  const float* Wk     = (const float*)d_in[6];
  const float* Wv     = (const float*)d_in[7];
  const float* Wo     = (const float*)d_in[8];
  const float* Tk     = (const float*)d_in[9];
  const float* Tv     = (const float*)d_in[10];
  float* out = (float*)d_out;

  float* ws   = (float*)d_ws;
  float* hbuf = ws;                                    // 32MB region, subdivided below
  float* kbuf = hbuf + (size_t)S_ * DM_;               // 8MB fp32 K pre-quant [kvh][s][d]
  float* vbuf = kbuf + (size_t)S_ * KVH_ * HD_;        // 8MB fp32 V pre-quant [kvh][s][d]
  float* Tkit = vbuf + (size_t)S_ * KVH_ * HD_;        // inv(Tk)^T
  float* TvI  = Tkit + 128 * 128;                      // inv(Tv)
  float* cosT = TvI + 128 * 128;                       // S*64
  float* sinT = cosT + (size_t)S_ * 64;                // S*64
  ushort_t* hb16 = (ushort_t*)(sinT + (size_t)S_ * 64);   // 16MB bf16 (LN hi; later attn out)
  ushort_t* WT   = hb16 + (size_t)S_ * DM_;               // 32MB bf16 (WqT | KV hi+lo | WoT')
  float* nb      = (float*)(WT + (size_t)DM_ * DM_);      // Newton: 6 x 16384 floats
  ushort_t* tfH  = (ushort_t*)(nb + 6 * 16384);           // 4 x 32KB B-frag hi
  ushort_t* tfL  = tfH + 4 * 16384;                       // 4 x 32KB B-frag lo
  ushort_t* RBh  = tfL + 4 * 16384;                       // 8KB each: R/L 64x64 frag packs
  ushort_t* RBl  = RBh + 4096;
  ushort_t* LBh  = RBl + 4096;
  ushort_t* LBl  = LBh + 4096;

  // subdivision of the 32MB hbuf region:
  char* hbytes = (char*)hbuf;
  ushort_t* hlo16 = (ushort_t*)hbytes;                    // [0,16MB)  LN lo (dead after gemm_bf16_3)
  ushort_t* qfrag = (ushort_t*)hbytes;                    // [0,16MB)  q fragment tiles
  ushort_t* kfrag = (ushort_t*)(hbytes + (16u << 20));    // [16,20MB) k fragment tiles
  ushort_t* vfrag = (ushort_t*)(hbytes + (20u << 20));    // [20,24MB) v fragment tiles

  ushort_t* WTkh = WT;
  ushort_t* WTkl = WT + (size_t)2048 * DM_;

  float* Xk = nb,              *Xv = nb + 16384;
  float* Yk = nb + 2 * 16384,  *Yv = nb + 3 * 16384;
  float* Xk2 = nb + 4 * 16384, *Xv2 = nb + 5 * 16384;

  float* qbuf = out;  // d_out as q scratch [H][S][128] fp32

  // ---- Newton inverse (4 iters): Tkit = inv(Tk)^T, TvI = inv(Tv)
  newton_init<<<dim3(2, 16), 1024, 0, stream>>>(Tk, Tv, Xk, Xv);
  for (int it = 0; it < 4; ++it) {
    nmm<<<dim3(4, 2), 256, 0, stream>>>(Tk, Xk, Yk, 0, Tv, Xv, Yv, 0, 0);
    const int last = (it == 3);
    float* ok = last ? Tkit : Xk2;
    float* ov = last ? TvI  : Xv2;
    nmm<<<dim3(4, 2), 256, 0, stream>>>(Xk, Yk, ok, last ? 1 : 0, Xv, Yv, ov, 0, 1);
    float* t;
    t = Xk; Xk = Xk2; Xk2 = t;
    t = Xv; Xv = Xv2; Xv2 = t;
  }
  prep_all<<<6, 256, 0, stream>>>(Tkit, Tk, Tv, TvI, lnR, lnL,
                                  tfH, tfL, RBh, RBl, LBh, LBl);

  rope_table<<<S_, 64, 0, stream>>>(pos, cosT, sinT);
  ln3<<<S_ / 4, 256, 0, stream>>>(hidden, RBh, RBl, LBh, LBl, hb16, hlo16);

  wtrans<<<dim3(DM_ / 64, DM_ / 64), 256, 0, stream>>>(Wq, WT, DM_, DM_);
  gemm_bf16<<<dim3(DM_ / 128, S_ / 128), 256, 0, stream>>>(hb16, WT, qbuf, S_, DM_, DM_, 1);
  wtrans_hl2<<<dim3(16, 64, 2), 256, 0, stream>>>(Wk, Wv, WTkh, WTkl);
  gemm_bf16_3<<<dim3(32, S_ / 128), 256, 0, stream>>>(hb16, hlo16, WTkh, WTkl,
                                                      kbuf, vbuf, S_, 2048, DM_);

  tpost_all<<<3072, 256, 0, stream>>>(qbuf, kbuf, vbuf, tfH, tfL,
                                      cosT, sinT, qfrag, kfrag, vfrag);

  attn_mfma7<<<dim3(S_ / 128 * H_), 256, 0, stream>>>(qfrag, kfrag, vfrag, hb16);

  wfold3<<<dim3(DM_ / 128, H_), 256, 0, stream>>>(Wo, tfH + 3 * 16384, tfL + 3 * 16384, WT);
  gemm_bf16<<<dim3(DM_ / 128, S_ / 128), 256, 0, stream>>>(hb16, WT, out, S_, DM_, DM_, 0);
}

// Round 16
// 576.321 us; speedup vs baseline: 1.0523x; 1.0523x over previous
//
#include <hip/hip_runtime.h>
#include <math.h>

#define S_    2048
#define DM_   4096
#define H_    32
#define KVH_  8
#define HD_   128

typedef __bf16 bf16x8 __attribute__((ext_vector_type(8)));
typedef float  f32x4  __attribute__((ext_vector_type(4)));
typedef unsigned short u16x8 __attribute__((ext_vector_type(8)));
typedef unsigned short ushort_t;

// float -> bf16 bits, round-to-nearest-even
__device__ __forceinline__ ushort_t f2b(float f) {
  unsigned int u = __float_as_uint(f);
  unsigned int r = (u + 0x7fffu + ((u >> 16) & 1u)) >> 16;
  return (ushort_t)r;
}
__device__ __forceinline__ float b2f(ushort_t h) {
  return __uint_as_float(((unsigned int)h) << 16);
}
__device__ __forceinline__ bf16x8 asbf(u16x8 v) {
  return __builtin_bit_cast(bf16x8, v);
}

// async global->LDS, 16 bytes per lane
__device__ __forceinline__ void gload16(const void* g, void* l) {
  __builtin_amdgcn_global_load_lds(
      (const __attribute__((address_space(1))) void*)g,
      (__attribute__((address_space(3))) void*)(unsigned int)(unsigned long long)l,
      16, 0, 0);
}

// ---------------- Newton inverse: X0 = 2I - A (both matrices) ----------------
__global__ void newton_init(const float* __restrict__ A0, const float* __restrict__ A1,
                            float* __restrict__ X0, float* __restrict__ X1)
{
  const float* A = blockIdx.x ? A1 : A0;
  float*       X = blockIdx.x ? X1 : X0;
  const int i = blockIdx.y * 1024 + threadIdx.x;
  const int r = i >> 7, c = i & 127;
  X[i] = ((r == c) ? 2.0f : 0.0f) - A[i];
}

// ---------------- 128x128 fp32 matmul, dual-matrix, Newton-step epilogue --------------
__global__ __launch_bounds__(256) void nmm(
    const float* __restrict__ A0, const float* __restrict__ B0, float* __restrict__ C0, int tr0,
    const float* __restrict__ A1, const float* __restrict__ B1, float* __restrict__ C1, int tr1,
    int update)
{
  const float* A = blockIdx.y ? A1 : A0;
  const float* B = blockIdx.y ? B1 : B0;
  float*       C = blockIdx.y ? C1 : C0;
  const int tr   = blockIdx.y ? tr1 : tr0;
  const int m0   = blockIdx.x * 32;
  const int tid  = threadIdx.x;

  __shared__ float Bs[128][132];
  __shared__ float As[32][132];

#pragma unroll
  for (int i = 0; i < 16; ++i) {
    int idx = tid + i * 256;
    int row = idx >> 5, c4 = (idx & 31) * 4;
    *(float4*)&Bs[row][c4] = *(const float4*)&B[row * 128 + c4];
  }
#pragma unroll
  for (int i = 0; i < 4; ++i) {
    int idx = tid + i * 256;
    int row = idx >> 5, c4 = (idx & 31) * 4;
    *(float4*)&As[row][c4] = *(const float4*)&A[(m0 + row) * 128 + c4];
  }
  __syncthreads();

  const int rloc = tid >> 3;
  const int c0   = (tid & 7) * 16;
  float acc[16];
#pragma unroll
  for (int j = 0; j < 16; ++j) acc[j] = 0.0f;
  for (int k = 0; k < 128; ++k) {
    float a = As[rloc][k];
#pragma unroll
    for (int j = 0; j < 16; j += 4) {
      float4 bv = *(const float4*)&Bs[k][c0 + j];
      acc[j + 0] += a * bv.x; acc[j + 1] += a * bv.y;
      acc[j + 2] += a * bv.z; acc[j + 3] += a * bv.w;
    }
  }
#pragma unroll
  for (int j = 0; j < 16; ++j) {
    float v = update ? (2.0f * As[rloc][c0 + j] - acc[j]) : acc[j];
    if (tr) C[(c0 + j) * 128 + (m0 + rloc)] = v;
    else    C[(m0 + rloc) * 128 + c0 + j]   = v;
  }
}

// ---------------- prep_all: fragment packs for T matrices + LN R/L -------------------
__global__ void prep_all(const float* __restrict__ Tkit, const float* __restrict__ Tk,
                         const float* __restrict__ Tv,   const float* __restrict__ TvI,
                         const float* __restrict__ lnR,  const float* __restrict__ lnL,
                         ushort_t* __restrict__ Fhi, ushort_t* __restrict__ Flo,
                         ushort_t* __restrict__ RBh, ushort_t* __restrict__ RBl,
                         ushort_t* __restrict__ LBh, ushort_t* __restrict__ LBl)
{
  const int mat = blockIdx.x;   // 0..5
  const int t   = threadIdx.x;  // 256
  if (mat < 4) {
    const float* src = (mat == 0) ? Tkit : ((mat == 1) ? Tk : ((mat == 2) ? Tv : TvI));
    const int tr = (mat == 3);
    ushort_t* hi = Fhi + mat * 16384;
    ushort_t* lo = Flo + mat * 16384;
    for (int ch = 0; ch < 32; ++ch) {
      int nt = ch >> 2, ds = ch & 3;
#pragma unroll
      for (int i = 0; i < 2; ++i) {
        int idx = t + i * 256;            // 0..511
        int ln = idx >> 3, j = idx & 7;
        int cc = ln & 15, gg = ln >> 4;
        int d = ds * 32 + gg * 8 + j, n = nt * 16 + cc;
        float x = tr ? src[n * 128 + d] : src[d * 128 + n];
        ushort_t hb = f2b(x);
        hi[(ch << 9) + idx] = hb;
        lo[(ch << 9) + idx] = f2b(x - b2f(hb));
      }
    }
  } else {
    const float* src = (mat == 4) ? lnR : lnL;
    ushort_t* hp = (mat == 4) ? RBh : LBh;
    ushort_t* lp = (mat == 4) ? RBl : LBl;
    for (int ch = 0; ch < 8; ++ch) {
      int nt = ch >> 1, ds = ch & 1;
#pragma unroll
      for (int i = 0; i < 2; ++i) {
        int idx = t + i * 256;
        int ln = idx >> 3, j = idx & 7;
        int cc = ln & 15, gg = ln >> 4;
        float x = src[(ds * 32 + gg * 8 + j) * 64 + nt * 16 + cc];
        ushort_t hb = f2b(x);
        hp[(ch << 9) + idx] = hb;
        lp[(ch << 9) + idx] = f2b(x - b2f(hb));
      }
    }
  }
}

// ---------------- RoPE cos/sin table: exactly numpy fp32 math ----------------
__global__ void rope_table(const int* __restrict__ pos,
                           float* __restrict__ cosT, float* __restrict__ sinT)
{
  const int s = blockIdx.x, i = threadIdx.x;
  float invf = 1.0f / (float)pow(10000.0, (double)i * (1.0 / 64.0));
  float ang  = (float)pos[s] * invf;
  cosT[s * 64 + i] = cosf(ang);
  sinT[s * 64 + i] = sinf(ang);
}

// ---------------- ln3: bilinear LN via hi/lo 3-pass MFMA ----------------
__global__ __launch_bounds__(256) void ln3(
    const float* __restrict__ hid,
    const ushort_t* __restrict__ RBh, const ushort_t* __restrict__ RBl,
    const ushort_t* __restrict__ LBh, const ushort_t* __restrict__ LBl,
    ushort_t* __restrict__ hb16, ushort_t* __restrict__ hlo16)
{
  const int blk = blockIdx.x;     // 512
  const int tid = threadIdx.x;
  const int w = tid >> 6, lane = tid & 63;
  const int c = lane & 15, g = lane >> 4;

  __shared__ float Hs[4][64 * 68];

#pragma unroll
  for (int i = 0; i < 16; ++i) {
    int idx = tid + i * 256;
    int t = idx >> 10, e = idx & 1023;
    int l = e >> 4, r4 = (e & 15) * 4;
    *(float4*)&Hs[t][l * 68 + r4] =
        *(const float4*)&hid[((size_t)(blk * 4 + t)) * 4096 + l * 64 + r4];
  }
  __syncthreads();

  float* Hw = Hs[w];

  u16x8 ah[4][2], al[4][2];
#pragma unroll
  for (int mt = 0; mt < 4; ++mt)
#pragma unroll
    for (int ds = 0; ds < 2; ++ds) {
      u16x8 th, tl;
#pragma unroll
      for (int j = 0; j < 8; ++j) {
        float x = Hw[(mt * 16 + c) * 68 + ds * 32 + g * 8 + j];
        ushort_t hb = f2b(x); th[j] = hb; tl[j] = f2b(x - b2f(hb));
      }
      ah[mt][ds] = th; al[mt][ds] = tl;
    }

  f32x4 acc[4][4];
#pragma unroll
  for (int mt = 0; mt < 4; ++mt)
#pragma unroll
    for (int nt = 0; nt < 4; ++nt) acc[mt][nt] = (f32x4){0.f, 0.f, 0.f, 0.f};
#pragma unroll
  for (int nt = 0; nt < 4; ++nt) {
    u16x8 bh[2], bl[2];
#pragma unroll
    for (int ds = 0; ds < 2; ++ds) {
      bh[ds] = *(const u16x8*)(RBh + ((nt * 2 + ds) << 9) + lane * 8);
      bl[ds] = *(const u16x8*)(RBl + ((nt * 2 + ds) << 9) + lane * 8);
    }
#pragma unroll
    for (int mt = 0; mt < 4; ++mt)
#pragma unroll
      for (int ds = 0; ds < 2; ++ds) {
        acc[mt][nt] = __builtin_amdgcn_mfma_f32_16x16x32_bf16(asbf(ah[mt][ds]), asbf(bh[ds]), acc[mt][nt], 0, 0, 0);
        acc[mt][nt] = __builtin_amdgcn_mfma_f32_16x16x32_bf16(asbf(ah[mt][ds]), asbf(bl[ds]), acc[mt][nt], 0, 0, 0);
        acc[mt][nt] = __builtin_amdgcn_mfma_f32_16x16x32_bf16(asbf(al[mt][ds]), asbf(bh[ds]), acc[mt][nt], 0, 0, 0);
      }
  }

#pragma unroll
  for (int mt = 0; mt < 4; ++mt)
#pragma unroll
    for (int nt = 0; nt < 4; ++nt)
#pragma unroll
      for (int reg = 0; reg < 4; ++reg)
        Hw[(mt * 16 + g * 4 + reg) * 68 + nt * 16 + c] = acc[mt][nt][reg];

  u16x8 a2h[4][2], a2l[4][2];
#pragma unroll
  for (int mt = 0; mt < 4; ++mt)
#pragma unroll
    for (int ds = 0; ds < 2; ++ds) {
      a2h[mt][ds] = *(const u16x8*)(LBh + ((mt * 2 + ds) << 9) + lane * 8);
      a2l[mt][ds] = *(const u16x8*)(LBl + ((mt * 2 + ds) << 9) + lane * 8);
    }
  f32x4 acc2[4][4];
#pragma unroll
  for (int mt = 0; mt < 4; ++mt)
#pragma unroll
    for (int nt = 0; nt < 4; ++nt) acc2[mt][nt] = (f32x4){0.f, 0.f, 0.f, 0.f};
#pragma unroll
  for (int nt = 0; nt < 4; ++nt) {
#pragma unroll
    for (int ds = 0; ds < 2; ++ds) {
      u16x8 bh, bl;
#pragma unroll
      for (int j = 0; j < 8; ++j) {
        float x = Hw[(ds * 32 + g * 8 + j) * 68 + nt * 16 + c];
        ushort_t hb = f2b(x); bh[j] = hb; bl[j] = f2b(x - b2f(hb));
      }
#pragma unroll
      for (int mt = 0; mt < 4; ++mt) {
        acc2[mt][nt] = __builtin_amdgcn_mfma_f32_16x16x32_bf16(asbf(a2h[mt][ds]), asbf(bh), acc2[mt][nt], 0, 0, 0);
        acc2[mt][nt] = __builtin_amdgcn_mfma_f32_16x16x32_bf16(asbf(a2h[mt][ds]), asbf(bl), acc2[mt][nt], 0, 0, 0);
        acc2[mt][nt] = __builtin_amdgcn_mfma_f32_16x16x32_bf16(asbf(a2l[mt][ds]), asbf(bh), acc2[mt][nt], 0, 0, 0);
      }
    }
  }

  ushort_t* hp = (ushort_t*)Hw;       // hi plane [64][64]; lo plane at +4096
#pragma unroll
  for (int mt = 0; mt < 4; ++mt)
#pragma unroll
    for (int nt = 0; nt < 4; ++nt)
#pragma unroll
      for (int reg = 0; reg < 4; ++reg) {
        int a = mt * 16 + g * 4 + reg, cc2 = nt * 16 + c;
        float v = acc2[mt][nt][reg];
        ushort_t hb = f2b(v);
        hp[a * 64 + cc2] = hb;
        hp[4096 + a * 64 + cc2] = f2b(v - b2f(hb));
      }

  const size_t sbase = ((size_t)(blk * 4 + w)) * 4096;
#pragma unroll
  for (int i = 0; i < 8; ++i) {
    int idx = i * 64 + lane;
    int row = idx >> 3, c8 = (idx & 7) * 8;
    *(u16x8*)&hb16[sbase + row * 64 + c8]  = *(const u16x8*)&hp[row * 64 + c8];
    *(u16x8*)&hlo16[sbase + row * 64 + c8] = *(const u16x8*)&hp[4096 + row * 64 + c8];
  }
}

// ---------------- weight transpose + bf16 cast (hi only): W[K][N] -> WT[N][K] ----------
__global__ void wtrans(const float* __restrict__ W, ushort_t* __restrict__ WT,
                       int K, int N)
{
  __shared__ ushort_t t[64][68];
  const int tid = threadIdx.x;
  const int n0 = blockIdx.x * 64, k0 = blockIdx.y * 64;
  for (int idx = tid; idx < 4096; idx += 256) {
    int rr = idx >> 6, cc = idx & 63;
    t[cc][rr] = f2b(W[(size_t)(k0 + rr) * N + n0 + cc]);
  }
  __syncthreads();
  for (int idx = tid; idx < 4096; idx += 256) {
    int rr = idx >> 6, cc = idx & 63;
    WT[(size_t)(n0 + rr) * K + k0 + cc] = t[rr][cc];
  }
}

// ---------------- weight transpose + hi/lo split, z selects Wk(0)/Wv(1) --------------
__global__ void wtrans_hl2(const float* __restrict__ Wk, const float* __restrict__ Wv,
                           ushort_t* __restrict__ WThi, ushort_t* __restrict__ WTlo)
{
  const int which = blockIdx.z;
  const float* W = which ? Wv : Wk;
  const int rowoff = which ? 1024 : 0;
  const int K = DM_, N = 1024;
  __shared__ ushort_t th[64][68];
  __shared__ ushort_t tl[64][68];
  const int tid = threadIdx.x;
  const int n0 = blockIdx.x * 64, k0 = blockIdx.y * 64;
  for (int idx = tid; idx < 4096; idx += 256) {
    int rr = idx >> 6, cc = idx & 63;
    float x = W[(size_t)(k0 + rr) * N + n0 + cc];
    ushort_t h = f2b(x);
    th[cc][rr] = h;
    tl[cc][rr] = f2b(x - b2f(h));
  }
  __syncthreads();
  for (int idx = tid; idx < 4096; idx += 256) {
    int rr = idx >> 6, cc = idx & 63;
    size_t o = (size_t)(rowoff + n0 + rr) * K + k0 + cc;
    WThi[o] = th[rr][cc];
    WTlo[o] = tl[rr][cc];
  }
}

// ---------------- wfold3: MFMA hi/lo 3-pass fold of TvI into Wo ----------------
__global__ __launch_bounds__(256) void wfold3(
    const float* __restrict__ Wo,
    const ushort_t* __restrict__ TBh, const ushort_t* __restrict__ TBl,
    ushort_t* __restrict__ WT)
{
  const int n0 = blockIdx.x * 128;
  const int h  = blockIdx.y;
  const int tid = threadIdx.x;
  const int w = tid >> 6, lane = tid & 63;
  const int c = lane & 15, g = lane >> 4;

  __shared__ float WoS[128 * 132];

#pragma unroll
  for (int i = 0; i < 16; ++i) {
    int idx = tid + i * 256;
    int e = idx >> 5, n4 = (idx & 31) * 4;
    *(float4*)&WoS[e * 132 + n4] =
        *(const float4*)&Wo[(size_t)(h * 128 + e) * 4096 + n0 + n4];
  }
  __syncthreads();

  u16x8 ah[2][4], al[2][4];
#pragma unroll
  for (int mt = 0; mt < 2; ++mt)
#pragma unroll
    for (int ds = 0; ds < 4; ++ds) {
      u16x8 th, tl;
#pragma unroll
      for (int j = 0; j < 8; ++j) {
        float x = WoS[(ds * 32 + g * 8 + j) * 132 + w * 32 + mt * 16 + c];
        ushort_t hb = f2b(x); th[j] = hb; tl[j] = f2b(x - b2f(hb));
      }
      ah[mt][ds] = th; al[mt][ds] = tl;
    }

  f32x4 acc[2][8];
#pragma unroll
  for (int mt = 0; mt < 2; ++mt)
#pragma unroll
    for (int nt = 0; nt < 8; ++nt) acc[mt][nt] = (f32x4){0.f, 0.f, 0.f, 0.f};
#pragma unroll
  for (int nt = 0; nt < 8; ++nt) {
#pragma unroll
    for (int ds = 0; ds < 4; ++ds) {
      u16x8 bh = *(const u16x8*)(TBh + ((nt * 4 + ds) << 9) + lane * 8);
      u16x8 bl = *(const u16x8*)(TBl + ((nt * 4 + ds) << 9) + lane * 8);
#pragma unroll
      for (int mt = 0; mt < 2; ++mt) {
        acc[mt][nt] = __builtin_amdgcn_mfma_f32_16x16x32_bf16(asbf(ah[mt][ds]), asbf(bh), acc[mt][nt], 0, 0, 0);
        acc[mt][nt] = __builtin_amdgcn_mfma_f32_16x16x32_bf16(asbf(ah[mt][ds]), asbf(bl), acc[mt][nt], 0, 0, 0);
        acc[mt][nt] = __builtin_amdgcn_mfma_f32_16x16x32_bf16(asbf(al[mt][ds]), asbf(bh), acc[mt][nt], 0, 0, 0);
      }
    }
  }
  __syncthreads();

  ushort_t* OS = (ushort_t*)WoS;
#pragma unroll
  for (int mt = 0; mt < 2; ++mt)
#pragma unroll
    for (int nt = 0; nt < 8; ++nt)
#pragma unroll
      for (int reg = 0; reg < 4; ++reg)
        OS[(w * 32 + mt * 16 + g * 4 + reg) * 136 + nt * 16 + c] = f2b(acc[mt][nt][reg]);
  __syncthreads();

#pragma unroll
  for (int i = 0; i < 8; ++i) {
    int idx = tid + i * 256;
    int nn = idx >> 4, c8 = (idx & 15) * 8;
    *(u16x8*)&WT[(size_t)(n0 + nn) * 4096 + h * 128 + c8] = *(const u16x8*)&OS[nn * 136 + c8];
  }
}

// ---------------- bf16 MFMA GEMM (m97 structure): C = A x BT^T ----------------
__global__ __launch_bounds__(256) void gemm_bf16(const ushort_t* __restrict__ A,
                                                 const ushort_t* __restrict__ BT,
                                                 float* __restrict__ C,
                                                 int M, int N, int K, int qlayout)
{
  __shared__ __align__(16) ushort_t As[128 * 64];
  __shared__ __align__(16) ushort_t Bs[128 * 64];
  const int tid = threadIdx.x;
  const int bm = blockIdx.y * 128, bn = blockIdx.x * 128;
  const int lane = tid & 63, w = tid >> 6;
  const int c = lane & 15, g = lane >> 4;
  const int wm = (w >> 1) * 64, wn = (w & 1) * 64;
  f32x4 acc[4][4];
#pragma unroll
  for (int mt = 0; mt < 4; ++mt)
#pragma unroll
    for (int nt = 0; nt < 4; ++nt) acc[mt][nt] = (f32x4){0.f, 0.f, 0.f, 0.f};
  const int srow = tid >> 3;
  const int slot = (tid & 7) ^ (srow & 7);
  for (int k0 = 0; k0 < K; k0 += 64) {
    __syncthreads();
#pragma unroll
    for (int ii = 0; ii < 4; ++ii) {
      gload16(A  + (size_t)(bm + ii * 32 + srow) * K + k0 + slot * 8,
              (char*)As + w * 1024 + ii * 4096);
      gload16(BT + (size_t)(bn + ii * 32 + srow) * K + k0 + slot * 8,
              (char*)Bs + w * 1024 + ii * 4096);
    }
    __syncthreads();
#pragma unroll
    for (int ks = 0; ks < 2; ++ks) {
      bf16x8 av[4], bv[4];
#pragma unroll
      for (int mt = 0; mt < 4; ++mt)
        av[mt] = *(const bf16x8*)((const char*)As + (wm + mt * 16 + c) * 128 +
                                  (((ks * 4 + g) ^ (c & 7)) << 4));
#pragma unroll
      for (int nt = 0; nt < 4; ++nt)
        bv[nt] = *(const bf16x8*)((const char*)Bs + (wn + nt * 16 + c) * 128 +
                                  (((ks * 4 + g) ^ (c & 7)) << 4));
#pragma unroll
      for (int mt = 0; mt < 4; ++mt)
#pragma unroll
        for (int nt = 0; nt < 4; ++nt)
          acc[mt][nt] = __builtin_amdgcn_mfma_f32_16x16x32_bf16(av[mt], bv[nt], acc[mt][nt], 0, 0, 0);
    }
  }
#pragma unroll
  for (int mt = 0; mt < 4; ++mt)
#pragma unroll
    for (int nt = 0; nt < 4; ++nt)
#pragma unroll
      for (int reg = 0; reg < 4; ++reg) {
        int m = bm + wm + mt * 16 + g * 4 + reg;
        int n = bn + wn + nt * 16 + c;
        float v = acc[mt][nt][reg];
        if (qlayout) C[((size_t)(n >> 7) * S_ + m) * 128 + (n & 127)] = v;
        else         C[(size_t)m * N + n] = v;
      }
}

// ---------------- 3-pass split-bf16 MFMA GEMM (near-fp32); out [kvh][s][d] ------------
__global__ __launch_bounds__(256) void gemm_bf16_3(
    const ushort_t* __restrict__ Ahi, const ushort_t* __restrict__ Alo,
    const ushort_t* __restrict__ BThi, const ushort_t* __restrict__ BTlo,
    float* __restrict__ Ck, float* __restrict__ Cv, int M, int N, int K)
{
  __shared__ __align__(16) ushort_t Ash[128 * 64];
  __shared__ __align__(16) ushort_t Asl[128 * 64];
  __shared__ __align__(16) ushort_t Bsh[64 * 64];
  __shared__ __align__(16) ushort_t Bsl[64 * 64];
  const int tid = threadIdx.x;
  const int bm = blockIdx.y * 128, bn = blockIdx.x * 64;
  const int lane = tid & 63, w = tid >> 6;
  const int c = lane & 15, g = lane >> 4;
  const int wm = w * 32;
  f32x4 acc[2][4];
#pragma unroll
  for (int mt = 0; mt < 2; ++mt)
#pragma unroll
    for (int nt = 0; nt < 4; ++nt) acc[mt][nt] = (f32x4){0.f, 0.f, 0.f, 0.f};
  const int srow = tid >> 3;
  const int slot = (tid & 7) ^ (srow & 7);
  for (int k0 = 0; k0 < K; k0 += 64) {
    __syncthreads();
#pragma unroll
    for (int ii = 0; ii < 4; ++ii) {
      const size_t ga = (size_t)(bm + ii * 32 + srow) * K + k0 + slot * 8;
      gload16(Ahi + ga, (char*)Ash + w * 1024 + ii * 4096);
      gload16(Alo + ga, (char*)Asl + w * 1024 + ii * 4096);
    }
#pragma unroll
    for (int ii = 0; ii < 2; ++ii) {
      const size_t gb = (size_t)(bn + ii * 32 + srow) * K + k0 + slot * 8;
      gload16(BThi + gb, (char*)Bsh + w * 1024 + ii * 4096);
      gload16(BTlo + gb, (char*)Bsl + w * 1024 + ii * 4096);
    }
    __syncthreads();
#pragma unroll
    for (int ks = 0; ks < 2; ++ks) {
      bf16x8 ah[2], al[2], bh[4], bl[4];
#pragma unroll
      for (int mt = 0; mt < 2; ++mt) {
        int ro = (wm + mt * 16 + c) * 128;
        int so = ((ks * 4 + g) ^ (c & 7)) << 4;
        ah[mt] = *(const bf16x8*)((const char*)Ash + ro + so);
        al[mt] = *(const bf16x8*)((const char*)Asl + ro + so);
      }
#pragma unroll
      for (int nt = 0; nt < 4; ++nt) {
        int ro = (nt * 16 + c) * 128;
        int so = ((ks * 4 + g) ^ (c & 7)) << 4;
        bh[nt] = *(const bf16x8*)((const char*)Bsh + ro + so);
        bl[nt] = *(const bf16x8*)((const char*)Bsl + ro + so);
      }
#pragma unroll
      for (int mt = 0; mt < 2; ++mt)
#pragma unroll
        for (int nt = 0; nt < 4; ++nt) {
          acc[mt][nt] = __builtin_amdgcn_mfma_f32_16x16x32_bf16(ah[mt], bh[nt], acc[mt][nt], 0, 0, 0);
          acc[mt][nt] = __builtin_amdgcn_mfma_f32_16x16x32_bf16(ah[mt], bl[nt], acc[mt][nt], 0, 0, 0);
          acc[mt][nt] = __builtin_amdgcn_mfma_f32_16x16x32_bf16(al[mt], bh[nt], acc[mt][nt], 0, 0, 0);
        }
    }
  }
#pragma unroll
  for (int mt = 0; mt < 2; ++mt)
#pragma unroll
    for (int nt = 0; nt < 4; ++nt)
#pragma unroll
      for (int reg = 0; reg < 4; ++reg) {
        int m = bm + wm + mt * 16 + g * 4 + reg;
        int n = bn + nt * 16 + c;
        float v = acc[mt][nt][reg];
        if (n < 1024) Ck[((size_t)(n >> 7) * S_ + m) * 128 + (n & 127)] = v;
        else          Cv[((size_t)((n - 1024) >> 7) * S_ + m) * 128 + (n & 127)] = v;
      }
}

// ---------------- tpost_all: merged q/k/v post (rope + @T + scale/quant + frag store) --
__global__ __launch_bounds__(256) void tpost_all(
    const float* __restrict__ qsrc, const float* __restrict__ ksrc,
    const float* __restrict__ vsrc,
    const ushort_t* __restrict__ tfH, const ushort_t* __restrict__ tfL,
    const float* __restrict__ cosT, const float* __restrict__ sinT,
    ushort_t* __restrict__ qfrag, ushort_t* __restrict__ kfrag,
    ushort_t* __restrict__ vfrag)
{
  const int b = blockIdx.x;        // 0..3071
  const float* src; const ushort_t *Thi, *Tlo; ushort_t* outp; int mode, blk;
  if (b < 2048)      { src = qsrc; Thi = tfH;             Tlo = tfL;             outp = qfrag; mode = 0; blk = b; }
  else if (b < 2560) { src = ksrc; Thi = tfH + 16384;     Tlo = tfL + 16384;     outp = kfrag; mode = 1; blk = b - 2048; }
  else               { src = vsrc; Thi = tfH + 2 * 16384; Tlo = tfL + 2 * 16384; outp = vfrag; mode = 2; blk = b - 2560; }

  const int tid = threadIdx.x;
  const int w = tid >> 6, lane = tid & 63;
  const int c = lane & 15, g = lane >> 4;

  __shared__ float raw_[32 * 132];
  __shared__ float rop_[32 * 132];
  __shared__ __align__(16) ushort_t vtile[32][136];

#pragma unroll
  for (int i = 0; i < 4; ++i) {
    int idx = tid + i * 256;
    int row = idx >> 5, c4 = (idx & 31) * 4;
    *(float4*)&raw_[row * 132 + c4] =
        *(const float4*)&src[(size_t)(blk * 32 + row) * 128 + c4];
  }
  __syncthreads();

  {
    const int r = tid >> 3, co = (tid & 7) * 16;
    if (mode <= 1) {
      const int s = (blk & 63) * 32 + r;
      const float* ct = cosT + (size_t)s * 64;
      const float* st = sinT + (size_t)s * 64;
#pragma unroll
      for (int j = 0; j < 16; ++j) {
        int cc = co + j, i2 = cc & 63;
        float x = raw_[r * 132 + cc];
        float other = (cc < 64) ? raw_[r * 132 + cc + 64] : raw_[r * 132 + cc - 64];
        rop_[r * 132 + cc] = (cc < 64) ? (x * ct[i2] - other * st[i2])
                                       : (x * ct[i2] + other * st[i2]);
      }
    } else {
#pragma unroll
      for (int j = 0; j < 16; ++j) {
        int cc = co + j;
        rop_[r * 132 + cc] = raw_[r * 132 + cc];
      }
    }
  }
  __syncthreads();

  u16x8 ahu[2][4], alu[2][4];
#pragma unroll
  for (int mt = 0; mt < 2; ++mt)
#pragma unroll
    for (int ds = 0; ds < 4; ++ds) {
      u16x8 th, tl;
#pragma unroll
      for (int j = 0; j < 8; ++j) {
        float x = rop_[(mt * 16 + c) * 132 + ds * 32 + g * 8 + j];
        ushort_t hb = f2b(x);
        th[j] = hb;
        tl[j] = f2b(x - b2f(hb));
      }
      ahu[mt][ds] = th;
      alu[mt][ds] = tl;
    }

  f32x4 acc[2][2];
#pragma unroll
  for (int mt = 0; mt < 2; ++mt)
#pragma unroll
    for (int nl = 0; nl < 2; ++nl) acc[mt][nl] = (f32x4){0.f, 0.f, 0.f, 0.f};
#pragma unroll
  for (int nl = 0; nl < 2; ++nl) {
    const int nt = w * 2 + nl;
    u16x8 bh[4], bl[4];
#pragma unroll
    for (int ds = 0; ds < 4; ++ds) {
      bh[ds] = *(const u16x8*)(Thi + ((nt * 4 + ds) << 9) + lane * 8);
      bl[ds] = *(const u16x8*)(Tlo + ((nt * 4 + ds) << 9) + lane * 8);
    }
#pragma unroll
    for (int mt = 0; mt < 2; ++mt)
#pragma unroll
      for (int ds = 0; ds < 4; ++ds) {
        acc[mt][nl] = __builtin_amdgcn_mfma_f32_16x16x32_bf16(asbf(ahu[mt][ds]), asbf(bh[ds]), acc[mt][nl], 0, 0, 0);
        acc[mt][nl] = __builtin_amdgcn_mfma_f32_16x16x32_bf16(asbf(ahu[mt][ds]), asbf(bl[ds]), acc[mt][nl], 0, 0, 0);
        acc[mt][nl] = __builtin_amdgcn_mfma_f32_16x16x32_bf16(asbf(alu[mt][ds]), asbf(bh[ds]), acc[mt][nl], 0, 0, 0);
      }
  }
  __syncthreads();

#pragma unroll
  for (int mt = 0; mt < 2; ++mt)
#pragma unroll
    for (int nl = 0; nl < 2; ++nl)
#pragma unroll
      for (int reg = 0; reg < 4; ++reg)
        raw_[(mt * 16 + g * 4 + reg) * 132 + (w * 2 + nl) * 16 + c] = acc[mt][nl][reg];
  __syncthreads();

  const int r = tid >> 3, co = (tid & 7) * 16;
  float vals[16];
#pragma unroll
  for (int j = 0; j < 16; ++j) vals[j] = raw_[r * 132 + co + j];

  if (mode == 0) {
#pragma unroll
    for (int j = 0; j < 16; ++j) vals[j] *= 0.08838834764831845f;
  } else {
    float m = 0.0f;
#pragma unroll
    for (int j = 0; j < 16; ++j) m = fmaxf(m, fabsf(vals[j]));
    m = fmaxf(m, __shfl_xor(m, 1));
    m = fmaxf(m, __shfl_xor(m, 2));
    m = fmaxf(m, __shfl_xor(m, 4));
    const float sc = fmaxf(m * (1.0f / 7.0f), 1e-8f);
#pragma unroll
    for (int j = 0; j < 16; ++j) {
      float qv = rintf(vals[j] / sc);
      qv = fminf(7.0f, fmaxf(-7.0f, qv));
      vals[j] = qv * sc;
    }
  }

  if (mode <= 1) {
    const size_t chunkbase = ((size_t)blk << 13) +
                             ((size_t)((r >> 4) * 4 + (co >> 5)) << 10);
    const int lane0 = ((co >> 3) & 3) * 16 + (r & 15);
    const int lane1 = (((co + 8) >> 3) & 3) * 16 + (r & 15);
    u16x8 o0, o1;
#pragma unroll
    for (int j = 0; j < 8; ++j) { o0[j] = f2b(vals[j]); o1[j] = f2b(vals[j + 8]); }
    *(u16x8*)((char*)outp + chunkbase + lane0 * 16) = o0;
    *(u16x8*)((char*)outp + chunkbase + lane1 * 16) = o1;
  } else {
#pragma unroll
    for (int j = 0; j < 16; ++j) vtile[r][co + j] = f2b(vals[j]);
    __syncthreads();
#pragma unroll
    for (int i = 0; i < 2; ++i) {
      int id = tid + i * 256;
      int dt = id >> 6, ln = id & 63;
      int gg = ln >> 4, cc = ln & 15;
      u16x8 o;
#pragma unroll
      for (int j = 0; j < 8; ++j) o[j] = vtile[gg * 8 + j][dt * 16 + cc];
      *(u16x8*)(outp + (((size_t)blk) << 12) + (dt << 9) + ln * 8) = o;
    }
  }
}

// ---------------- MFMA flash attention v6 (round-10 proven body: no prefetch) --------
__global__ __launch_bounds__(256) void attn_mfma6(
    const ushort_t* __restrict__ qf_,
    const ushort_t* __restrict__ kf_,
    const ushort_t* __restrict__ vf_,
    ushort_t* __restrict__ o16)
{
  const int lid = blockIdx.x;
  const int xcd = lid & 7;
  const int idx = lid >> 3;
  const int h   = xcd * 4 + (idx & 3);
  const int kb  = idx >> 2;
  const int kvh = xcd;

  const int tid = threadIdx.x;
  const int w    = tid >> 6;
  const int lane = tid & 63;
  const int c = lane & 15, g = lane >> 4;
  const int qt = (w < 2) ? (2 * kb + w) : (60 - 2 * kb + w);

  __shared__ __align__(16) ushort_t Ps[4][2][16][40];

  const float LOG2E = 1.44269504f;
  const float MBIAS = 28.8539008f;    // p = 2^(s*log2e - MBIAS) = e^(s-20)

  const char* qtile = (const char*)qf_ + (((size_t)(h * 64 + qt)) << 13);
  bf16x8 qf[2][4];
#pragma unroll
  for (int mt = 0; mt < 2; ++mt)
#pragma unroll
    for (int ds = 0; ds < 4; ++ds)
      qf[mt][ds] = *(const bf16x8*)(qtile + ((mt * 4 + ds) << 10) + lane * 16);

  bf16x8 ones;
#pragma unroll
  for (int j = 0; j < 8; ++j) ones[j] = (__bf16)1.0f;

  f32x4 oa[2][8];
#pragma unroll
  for (int mt = 0; mt < 2; ++mt)
#pragma unroll
    for (int dt = 0; dt < 8; ++dt) oa[mt][dt] = (f32x4){0.f, 0.f, 0.f, 0.f};
  f32x4 la[2];
  la[0] = (f32x4){0.f, 0.f, 0.f, 0.f};
  la[1] = (f32x4){0.f, 0.f, 0.f, 0.f};

  const char* kbase = (const char*)kf_ + (((size_t)kvh * 64) << 13);
  const char* vbase = (const char*)vf_ + (((size_t)kvh * 64) << 13);

  for (int kt = 0; kt <= qt; ++kt) {
    const char* ktile = kbase + ((size_t)kt << 13);
    const char* vtile = vbase + ((size_t)kt << 13);
    bf16x8 kc[2][4], vc[8];
#pragma unroll
    for (int nt = 0; nt < 2; ++nt)
#pragma unroll
      for (int ds = 0; ds < 4; ++ds)
        kc[nt][ds] = *(const bf16x8*)(ktile + ((nt * 4 + ds) << 10) + lane * 16);
#pragma unroll
    for (int dt = 0; dt < 8; ++dt)
      vc[dt] = *(const bf16x8*)(vtile + (dt << 10) + lane * 16);

    f32x4 sc[2][2];
#pragma unroll
    for (int mt = 0; mt < 2; ++mt)
#pragma unroll
      for (int nt = 0; nt < 2; ++nt) sc[mt][nt] = (f32x4){0.f, 0.f, 0.f, 0.f};
    __builtin_amdgcn_s_setprio(1);
#pragma unroll
    for (int ds = 0; ds < 4; ++ds) {
      sc[0][0] = __builtin_amdgcn_mfma_f32_16x16x32_bf16(qf[0][ds], kc[0][ds], sc[0][0], 0, 0, 0);
      sc[0][1] = __builtin_amdgcn_mfma_f32_16x16x32_bf16(qf[0][ds], kc[1][ds], sc[0][1], 0, 0, 0);
      sc[1][0] = __builtin_amdgcn_mfma_f32_16x16x32_bf16(qf[1][ds], kc[0][ds], sc[1][0], 0, 0, 0);
      sc[1][1] = __builtin_amdgcn_mfma_f32_16x16x32_bf16(qf[1][ds], kc[1][ds], sc[1][1], 0, 0, 0);
    }
    __builtin_amdgcn_s_setprio(0);

    // fixed-max softmax: p = e^(s-20); masked -> 0. No reductions, no rescale.
#pragma unroll
    for (int mt = 0; mt < 2; ++mt) {
#pragma unroll
      for (int reg = 0; reg < 4; ++reg) {
        float s0 = sc[mt][0][reg], s1 = sc[mt][1][reg];
        if (kt == qt) {
          int qrl = mt * 16 + g * 4 + reg;
          if (c > qrl)      s0 = -INFINITY;
          if (16 + c > qrl) s1 = -INFINITY;
        }
        float p0 = exp2f(s0 * LOG2E - MBIAS);
        float p1 = exp2f(s1 * LOG2E - MBIAS);
        Ps[w][mt][g * 4 + reg][c]      = f2b(p0);
        Ps[w][mt][g * 4 + reg][16 + c] = f2b(p1);
      }
    }

    bf16x8 pa0 = *reinterpret_cast<const bf16x8*>(&Ps[w][0][c][g * 8]);
    bf16x8 pa1 = *reinterpret_cast<const bf16x8*>(&Ps[w][1][c][g * 8]);
    __builtin_amdgcn_s_setprio(1);
#pragma unroll
    for (int dt = 0; dt < 8; ++dt) {
      oa[0][dt] = __builtin_amdgcn_mfma_f32_16x16x32_bf16(pa0, vc[dt], oa[0][dt], 0, 0, 0);
      oa[1][dt] = __builtin_amdgcn_mfma_f32_16x16x32_bf16(pa1, vc[dt], oa[1][dt], 0, 0, 0);
    }
    la[0] = __builtin_amdgcn_mfma_f32_16x16x32_bf16(pa0, ones, la[0], 0, 0, 0);
    la[1] = __builtin_amdgcn_mfma_f32_16x16x32_bf16(pa1, ones, la[1], 0, 0, 0);
    __builtin_amdgcn_s_setprio(0);
  }

#pragma unroll
  for (int mt = 0; mt < 2; ++mt)
#pragma unroll
    for (int reg = 0; reg < 4; ++reg) {
      float li = 1.0f / la[mt][reg];
      int srow = qt * 32 + mt * 16 + g * 4 + reg;
      ushort_t* orow = o16 + (size_t)srow * DM_ + h * 128;
#pragma unroll
      for (int dt = 0; dt < 8; ++dt)
        orow[dt * 16 + c] = f2b(oa[mt][dt][reg] * li);
    }
}

extern "C" void kernel_launch(void* const* d_in, const int* in_sizes, int n_in,
                              void* d_out, int out_size, void* d_ws, size_t ws_size,
                              hipStream_t stream)
{
  (void)in_sizes; (void)n_in; (void)out_size; (void)ws_size;
  const float* hidden = (const float*)d_in[0];
  const int*   pos    = (const int*)d_in[2];
  const float* lnL    = (const float*)d_in[3];
  const float* lnR    = (const float*)d_in[4];
  const float* Wq     = (const float*)d_in[5];
  const float* Wk     = (const float*)d_in[6];
  const float* Wv     = (const float*)d_in[7];
  const float* Wo     = (const float*)d_in[8];
  const float* Tk     = (const float*)d_in[9];
  const float* Tv     = (const float*)d_in[10];
  float* out = (float*)d_out;

  float* ws   = (float*)d_ws;
  float* hbuf = ws;                                    // 32MB region, subdivided below
  float* kbuf = hbuf + (size_t)S_ * DM_;               // 8MB fp32 K pre-quant [kvh][s][d]
  float* vbuf = kbuf + (size_t)S_ * KVH_ * HD_;        // 8MB fp32 V pre-quant [kvh][s][d]
  float* Tkit = vbuf + (size_t)S_ * KVH_ * HD_;        // inv(Tk)^T
  float* TvI  = Tkit + 128 * 128;                      // inv(Tv)
  float* cosT = TvI + 128 * 128;                       // S*64
  float* sinT = cosT + (size_t)S_ * 64;                // S*64
  ushort_t* hb16 = (ushort_t*)(sinT + (size_t)S_ * 64);   // 16MB bf16 (LN hi; later attn out)
  ushort_t* WT   = hb16 + (size_t)S_ * DM_;               // 32MB bf16 (WqT | KV hi+lo | WoT')
  float* nb      = (float*)(WT + (size_t)DM_ * DM_);      // Newton: 6 x 16384 floats
  ushort_t* tfH  = (ushort_t*)(nb + 6 * 16384);           // 4 x 32KB B-frag hi
  ushort_t* tfL  = tfH + 4 * 16384;                       // 4 x 32KB B-frag lo
  ushort_t* RBh  = tfL + 4 * 16384;                       // 8KB each: R/L 64x64 frag packs
  ushort_t* RBl  = RBh + 4096;
  ushort_t* LBh  = RBl + 4096;
  ushort_t* LBl  = LBh + 4096;

  // subdivision of the 32MB hbuf region:
  char* hbytes = (char*)hbuf;
  ushort_t* hlo16 = (ushort_t*)hbytes;                    // [0,16MB)  LN lo (dead after gemm_bf16_3)
  ushort_t* qfrag = (ushort_t*)hbytes;                    // [0,16MB)  q fragment tiles
  ushort_t* kfrag = (ushort_t*)(hbytes + (16u << 20));    // [16,20MB) k fragment tiles
  ushort_t* vfrag = (ushort_t*)(hbytes + (20u << 20));    // [20,24MB) v fragment tiles

  ushort_t* WTkh = WT;
  ushort_t* WTkl = WT + (size_t)2048 * DM_;

  float* Xk = nb,              *Xv = nb + 16384;
  float* Yk = nb + 2 * 16384,  *Yv = nb + 3 * 16384;
  float* Xk2 = nb + 4 * 16384, *Xv2 = nb + 5 * 16384;

  float* qbuf = out;  // d_out as q scratch [H][S][128] fp32

  // ---- Newton inverse (4 iters): Tkit = inv(Tk)^T, TvI = inv(Tv)
  newton_init<<<dim3(2, 16), 1024, 0, stream>>>(Tk, Tv, Xk, Xv);
  for (int it = 0; it < 4; ++it) {
    nmm<<<dim3(4, 2), 256, 0, stream>>>(Tk, Xk, Yk, 0, Tv, Xv, Yv, 0, 0);
    const int last = (it == 3);
    float* ok = last ? Tkit : Xk2;
    float* ov = last ? TvI  : Xv2;
    nmm<<<dim3(4, 2), 256, 0, stream>>>(Xk, Yk, ok, last ? 1 : 0, Xv, Yv, ov, 0, 1);
    float* t;
    t = Xk; Xk = Xk2; Xk2 = t;
    t = Xv; Xv = Xv2; Xv2 = t;
  }
  prep_all<<<6, 256, 0, stream>>>(Tkit, Tk, Tv, TvI, lnR, lnL,
                                  tfH, tfL, RBh, RBl, LBh, LBl);

  rope_table<<<S_, 64, 0, stream>>>(pos, cosT, sinT);
  ln3<<<S_ / 4, 256, 0, stream>>>(hidden, RBh, RBl, LBh, LBl, hb16, hlo16);

  wtrans<<<dim3(DM_ / 64, DM_ / 64), 256, 0, stream>>>(Wq, WT, DM_, DM_);
  gemm_bf16<<<dim3(DM_ / 128, S_ / 128), 256, 0, stream>>>(hb16, WT, qbuf, S_, DM_, DM_, 1);
  wtrans_hl2<<<dim3(16, 64, 2), 256, 0, stream>>>(Wk, Wv, WTkh, WTkl);
  gemm_bf16_3<<<dim3(32, S_ / 128), 256, 0, stream>>>(hb16, hlo16, WTkh, WTkl,
                                                      kbuf, vbuf, S_, 2048, DM_);

  tpost_all<<<3072, 256, 0, stream>>>(qbuf, kbuf, vbuf, tfH, tfL,
                                      cosT, sinT, qfrag, kfrag, vfrag);

  attn_mfma6<<<dim3(S_ / 128 * H_), 256, 0, stream>>>(qfrag, kfrag, vfrag, hb16);

  wfold3<<<dim3(DM_ / 128, H_), 256, 0, stream>>>(Wo, tfH + 3 * 16384, tfL + 3 * 16384, WT);
  gemm_bf16<<<dim3(DM_ / 128, S_ / 128), 256, 0, stream>>>(hb16, WT, out, S_, DM_, DM_, 0);
}

// Round 17
// 568.809 us; speedup vs baseline: 1.0662x; 1.0132x over previous
//
#include <hip/hip_runtime.h>
#include <math.h>

#define S_    2048
#define DM_   4096
#define H_    32
#define KVH_  8
#define HD_   128

typedef __bf16 bf16x8 __attribute__((ext_vector_type(8)));
typedef float  f32x4  __attribute__((ext_vector_type(4)));
typedef unsigned short u16x8 __attribute__((ext_vector_type(8)));
typedef unsigned short ushort_t;

// float -> bf16 bits, round-to-nearest-even
__device__ __forceinline__ ushort_t f2b(float f) {
  unsigned int u = __float_as_uint(f);
  unsigned int r = (u + 0x7fffu + ((u >> 16) & 1u)) >> 16;
  return (ushort_t)r;
}
__device__ __forceinline__ float b2f(ushort_t h) {
  return __uint_as_float(((unsigned int)h) << 16);
}
__device__ __forceinline__ bf16x8 asbf(u16x8 v) {
  return __builtin_bit_cast(bf16x8, v);
}

// async global->LDS, 16 bytes per lane
__device__ __forceinline__ void gload16(const void* g, void* l) {
  __builtin_amdgcn_global_load_lds(
      (const __attribute__((address_space(1))) void*)g,
      (__attribute__((address_space(3))) void*)(unsigned int)(unsigned long long)l,
      16, 0, 0);
}

// ---------------- Newton inverse: X0 = 2I - A (both matrices) ----------------
__global__ void newton_init(const float* __restrict__ A0, const float* __restrict__ A1,
                            float* __restrict__ X0, float* __restrict__ X1)
{
  const float* A = blockIdx.x ? A1 : A0;
  float*       X = blockIdx.x ? X1 : X0;
  const int i = blockIdx.y * 1024 + threadIdx.x;
  const int r = i >> 7, c = i & 127;
  X[i] = ((r == c) ? 2.0f : 0.0f) - A[i];
}

// ---------------- 128x128 fp32 matmul, dual-matrix, Newton-step epilogue --------------
__global__ __launch_bounds__(256) void nmm(
    const float* __restrict__ A0, const float* __restrict__ B0, float* __restrict__ C0, int tr0,
    const float* __restrict__ A1, const float* __restrict__ B1, float* __restrict__ C1, int tr1,
    int update)
{
  const float* A = blockIdx.y ? A1 : A0;
  const float* B = blockIdx.y ? B1 : B0;
  float*       C = blockIdx.y ? C1 : C0;
  const int tr   = blockIdx.y ? tr1 : tr0;
  const int m0   = blockIdx.x * 32;
  const int tid  = threadIdx.x;

  __shared__ float Bs[128][132];
  __shared__ float As[32][132];

#pragma unroll
  for (int i = 0; i < 16; ++i) {
    int idx = tid + i * 256;
    int row = idx >> 5, c4 = (idx & 31) * 4;
    *(float4*)&Bs[row][c4] = *(const float4*)&B[row * 128 + c4];
  }
#pragma unroll
  for (int i = 0; i < 4; ++i) {
    int idx = tid + i * 256;
    int row = idx >> 5, c4 = (idx & 31) * 4;
    *(float4*)&As[row][c4] = *(const float4*)&A[(m0 + row) * 128 + c4];
  }
  __syncthreads();

  const int rloc = tid >> 3;
  const int c0   = (tid & 7) * 16;
  float acc[16];
#pragma unroll
  for (int j = 0; j < 16; ++j) acc[j] = 0.0f;
  for (int k = 0; k < 128; ++k) {
    float a = As[rloc][k];
#pragma unroll
    for (int j = 0; j < 16; j += 4) {
      float4 bv = *(const float4*)&Bs[k][c0 + j];
      acc[j + 0] += a * bv.x; acc[j + 1] += a * bv.y;
      acc[j + 2] += a * bv.z; acc[j + 3] += a * bv.w;
    }
  }
#pragma unroll
  for (int j = 0; j < 16; ++j) {
    float v = update ? (2.0f * As[rloc][c0 + j] - acc[j]) : acc[j];
    if (tr) C[(c0 + j) * 128 + (m0 + rloc)] = v;
    else    C[(m0 + rloc) * 128 + c0 + j]   = v;
  }
}

// ---------------- prep_all: fragment packs for T matrices + LN R/L -------------------
__global__ void prep_all(const float* __restrict__ Tkit, const float* __restrict__ Tk,
                         const float* __restrict__ Tv,   const float* __restrict__ TvI,
                         const float* __restrict__ lnR,  const float* __restrict__ lnL,
                         ushort_t* __restrict__ Fhi, ushort_t* __restrict__ Flo,
                         ushort_t* __restrict__ RBh, ushort_t* __restrict__ RBl,
                         ushort_t* __restrict__ LBh, ushort_t* __restrict__ LBl)
{
  const int mat = blockIdx.x;   // 0..5
  const int t   = threadIdx.x;  // 256
  if (mat < 4) {
    const float* src = (mat == 0) ? Tkit : ((mat == 1) ? Tk : ((mat == 2) ? Tv : TvI));
    const int tr = (mat == 3);
    ushort_t* hi = Fhi + mat * 16384;
    ushort_t* lo = Flo + mat * 16384;
    for (int ch = 0; ch < 32; ++ch) {
      int nt = ch >> 2, ds = ch & 3;
#pragma unroll
      for (int i = 0; i < 2; ++i) {
        int idx = t + i * 256;            // 0..511
        int ln = idx >> 3, j = idx & 7;
        int cc = ln & 15, gg = ln >> 4;
        int d = ds * 32 + gg * 8 + j, n = nt * 16 + cc;
        float x = tr ? src[n * 128 + d] : src[d * 128 + n];
        ushort_t hb = f2b(x);
        hi[(ch << 9) + idx] = hb;
        lo[(ch << 9) + idx] = f2b(x - b2f(hb));
      }
    }
  } else {
    const float* src = (mat == 4) ? lnR : lnL;
    ushort_t* hp = (mat == 4) ? RBh : LBh;
    ushort_t* lp = (mat == 4) ? RBl : LBl;
    for (int ch = 0; ch < 8; ++ch) {
      int nt = ch >> 1, ds = ch & 1;
#pragma unroll
      for (int i = 0; i < 2; ++i) {
        int idx = t + i * 256;
        int ln = idx >> 3, j = idx & 7;
        int cc = ln & 15, gg = ln >> 4;
        float x = src[(ds * 32 + gg * 8 + j) * 64 + nt * 16 + cc];
        ushort_t hb = f2b(x);
        hp[(ch << 9) + idx] = hb;
        lp[(ch << 9) + idx] = f2b(x - b2f(hb));
      }
    }
  }
}

// ---------------- trans_all: Wq transpose (hi) + Wk/Wv transpose hi/lo ---------------
__global__ void trans_all(const float* __restrict__ Wq, const float* __restrict__ Wk,
                          const float* __restrict__ Wv,
                          ushort_t* __restrict__ WT,
                          ushort_t* __restrict__ WThi, ushort_t* __restrict__ WTlo)
{
  const int b = blockIdx.x;       // 0..6143
  const int tid = threadIdx.x;
  __shared__ ushort_t th[64][68];
  __shared__ ushort_t tl[64][68];
  if (b < 4096) {
    const int n0 = (b & 63) * 64, k0 = (b >> 6) * 64;
    for (int idx = tid; idx < 4096; idx += 256) {
      int rr = idx >> 6, cc = idx & 63;
      th[cc][rr] = f2b(Wq[(size_t)(k0 + rr) * DM_ + n0 + cc]);
    }
    __syncthreads();
    for (int idx = tid; idx < 4096; idx += 256) {
      int rr = idx >> 6, cc = idx & 63;
      WT[(size_t)(n0 + rr) * DM_ + k0 + cc] = th[rr][cc];
    }
  } else {
    const int b2 = b - 4096;          // 0..2047
    const int which = b2 >> 10;       // 0 Wk, 1 Wv
    const int b3 = b2 & 1023;
    const float* W = which ? Wv : Wk;
    const int rowoff = which ? 1024 : 0;
    const int n0 = (b3 & 15) * 64, k0 = (b3 >> 4) * 64;
    for (int idx = tid; idx < 4096; idx += 256) {
      int rr = idx >> 6, cc = idx & 63;
      float x = W[(size_t)(k0 + rr) * 1024 + n0 + cc];
      ushort_t h = f2b(x);
      th[cc][rr] = h;
      tl[cc][rr] = f2b(x - b2f(h));
    }
    __syncthreads();
    for (int idx = tid; idx < 4096; idx += 256) {
      int rr = idx >> 6, cc = idx & 63;
      size_t o = (size_t)(rowoff + n0 + rr) * DM_ + k0 + cc;
      WThi[o] = th[rr][cc];
      WTlo[o] = tl[rr][cc];
    }
  }
}

// ---------------- lnrope: ln3 (blocks 0..511) + rope table (blocks 512..1023) --------
__global__ __launch_bounds__(256) void lnrope(
    const float* __restrict__ hid, const int* __restrict__ pos,
    const ushort_t* __restrict__ RBh, const ushort_t* __restrict__ RBl,
    const ushort_t* __restrict__ LBh, const ushort_t* __restrict__ LBl,
    ushort_t* __restrict__ hb16, ushort_t* __restrict__ hlo16,
    float* __restrict__ cosT, float* __restrict__ sinT)
{
  __shared__ float Hs[4][64 * 68];
  const int bid = blockIdx.x;
  const int tid = threadIdx.x;

  if (bid >= 512) {
    const int s = (bid - 512) * 4 + (tid >> 6);
    const int i = tid & 63;
    float invf = 1.0f / (float)pow(10000.0, (double)i * (1.0 / 64.0));
    float ang  = (float)pos[s] * invf;
    cosT[s * 64 + i] = cosf(ang);
    sinT[s * 64 + i] = sinf(ang);
    return;
  }

  const int blk = bid;
  const int w = tid >> 6, lane = tid & 63;
  const int c = lane & 15, g = lane >> 4;

#pragma unroll
  for (int i = 0; i < 16; ++i) {
    int idx = tid + i * 256;
    int t = idx >> 10, e = idx & 1023;
    int l = e >> 4, r4 = (e & 15) * 4;
    *(float4*)&Hs[t][l * 68 + r4] =
        *(const float4*)&hid[((size_t)(blk * 4 + t)) * 4096 + l * 64 + r4];
  }
  __syncthreads();

  float* Hw = Hs[w];

  u16x8 ah[4][2], al[4][2];
#pragma unroll
  for (int mt = 0; mt < 4; ++mt)
#pragma unroll
    for (int ds = 0; ds < 2; ++ds) {
      u16x8 th, tl;
#pragma unroll
      for (int j = 0; j < 8; ++j) {
        float x = Hw[(mt * 16 + c) * 68 + ds * 32 + g * 8 + j];
        ushort_t hb = f2b(x); th[j] = hb; tl[j] = f2b(x - b2f(hb));
      }
      ah[mt][ds] = th; al[mt][ds] = tl;
    }

  f32x4 acc[4][4];
#pragma unroll
  for (int mt = 0; mt < 4; ++mt)
#pragma unroll
    for (int nt = 0; nt < 4; ++nt) acc[mt][nt] = (f32x4){0.f, 0.f, 0.f, 0.f};
#pragma unroll
  for (int nt = 0; nt < 4; ++nt) {
    u16x8 bh[2], bl[2];
#pragma unroll
    for (int ds = 0; ds < 2; ++ds) {
      bh[ds] = *(const u16x8*)(RBh + ((nt * 2 + ds) << 9) + lane * 8);
      bl[ds] = *(const u16x8*)(RBl + ((nt * 2 + ds) << 9) + lane * 8);
    }
#pragma unroll
    for (int mt = 0; mt < 4; ++mt)
#pragma unroll
      for (int ds = 0; ds < 2; ++ds) {
        acc[mt][nt] = __builtin_amdgcn_mfma_f32_16x16x32_bf16(asbf(ah[mt][ds]), asbf(bh[ds]), acc[mt][nt], 0, 0, 0);
        acc[mt][nt] = __builtin_amdgcn_mfma_f32_16x16x32_bf16(asbf(ah[mt][ds]), asbf(bl[ds]), acc[mt][nt], 0, 0, 0);
        acc[mt][nt] = __builtin_amdgcn_mfma_f32_16x16x32_bf16(asbf(al[mt][ds]), asbf(bh[ds]), acc[mt][nt], 0, 0, 0);
      }
  }

#pragma unroll
  for (int mt = 0; mt < 4; ++mt)
#pragma unroll
    for (int nt = 0; nt < 4; ++nt)
#pragma unroll
      for (int reg = 0; reg < 4; ++reg)
        Hw[(mt * 16 + g * 4 + reg) * 68 + nt * 16 + c] = acc[mt][nt][reg];

  u16x8 a2h[4][2], a2l[4][2];
#pragma unroll
  for (int mt = 0; mt < 4; ++mt)
#pragma unroll
    for (int ds = 0; ds < 2; ++ds) {
      a2h[mt][ds] = *(const u16x8*)(LBh + ((mt * 2 + ds) << 9) + lane * 8);
      a2l[mt][ds] = *(const u16x8*)(LBl + ((mt * 2 + ds) << 9) + lane * 8);
    }
  f32x4 acc2[4][4];
#pragma unroll
  for (int mt = 0; mt < 4; ++mt)
#pragma unroll
    for (int nt = 0; nt < 4; ++nt) acc2[mt][nt] = (f32x4){0.f, 0.f, 0.f, 0.f};
#pragma unroll
  for (int nt = 0; nt < 4; ++nt) {
#pragma unroll
    for (int ds = 0; ds < 2; ++ds) {
      u16x8 bh, bl;
#pragma unroll
      for (int j = 0; j < 8; ++j) {
        float x = Hw[(ds * 32 + g * 8 + j) * 68 + nt * 16 + c];
        ushort_t hb = f2b(x); bh[j] = hb; bl[j] = f2b(x - b2f(hb));
      }
#pragma unroll
      for (int mt = 0; mt < 4; ++mt) {
        acc2[mt][nt] = __builtin_amdgcn_mfma_f32_16x16x32_bf16(asbf(a2h[mt][ds]), asbf(bh), acc2[mt][nt], 0, 0, 0);
        acc2[mt][nt] = __builtin_amdgcn_mfma_f32_16x16x32_bf16(asbf(a2h[mt][ds]), asbf(bl), acc2[mt][nt], 0, 0, 0);
        acc2[mt][nt] = __builtin_amdgcn_mfma_f32_16x16x32_bf16(asbf(a2l[mt][ds]), asbf(bh), acc2[mt][nt], 0, 0, 0);
      }
    }
  }

  ushort_t* hp = (ushort_t*)Hw;       // hi plane [64][64]; lo plane at +4096
#pragma unroll
  for (int mt = 0; mt < 4; ++mt)
#pragma unroll
    for (int nt = 0; nt < 4; ++nt)
#pragma unroll
      for (int reg = 0; reg < 4; ++reg) {
        int a = mt * 16 + g * 4 + reg, cc2 = nt * 16 + c;
        float v = acc2[mt][nt][reg];
        ushort_t hb = f2b(v);
        hp[a * 64 + cc2] = hb;
        hp[4096 + a * 64 + cc2] = f2b(v - b2f(hb));
      }

  const size_t sbase = ((size_t)(blk * 4 + w)) * 4096;
#pragma unroll
  for (int i = 0; i < 8; ++i) {
    int idx = i * 64 + lane;
    int row = idx >> 3, c8 = (idx & 7) * 8;
    *(u16x8*)&hb16[sbase + row * 64 + c8]  = *(const u16x8*)&hp[row * 64 + c8];
    *(u16x8*)&hlo16[sbase + row * 64 + c8] = *(const u16x8*)&hp[4096 + row * 64 + c8];
  }
}

// ---------------- wfold3: MFMA hi/lo 3-pass fold of TvI into Wo ----------------
__global__ __launch_bounds__(256) void wfold3(
    const float* __restrict__ Wo,
    const ushort_t* __restrict__ TBh, const ushort_t* __restrict__ TBl,
    ushort_t* __restrict__ WT)
{
  const int n0 = blockIdx.x * 128;
  const int h  = blockIdx.y;
  const int tid = threadIdx.x;
  const int w = tid >> 6, lane = tid & 63;
  const int c = lane & 15, g = lane >> 4;

  __shared__ float WoS[128 * 132];

#pragma unroll
  for (int i = 0; i < 16; ++i) {
    int idx = tid + i * 256;
    int e = idx >> 5, n4 = (idx & 31) * 4;
    *(float4*)&WoS[e * 132 + n4] =
        *(const float4*)&Wo[(size_t)(h * 128 + e) * 4096 + n0 + n4];
  }
  __syncthreads();

  u16x8 ah[2][4], al[2][4];
#pragma unroll
  for (int mt = 0; mt < 2; ++mt)
#pragma unroll
    for (int ds = 0; ds < 4; ++ds) {
      u16x8 th, tl;
#pragma unroll
      for (int j = 0; j < 8; ++j) {
        float x = WoS[(ds * 32 + g * 8 + j) * 132 + w * 32 + mt * 16 + c];
        ushort_t hb = f2b(x); th[j] = hb; tl[j] = f2b(x - b2f(hb));
      }
      ah[mt][ds] = th; al[mt][ds] = tl;
    }

  f32x4 acc[2][8];
#pragma unroll
  for (int mt = 0; mt < 2; ++mt)
#pragma unroll
    for (int nt = 0; nt < 8; ++nt) acc[mt][nt] = (f32x4){0.f, 0.f, 0.f, 0.f};
#pragma unroll
  for (int nt = 0; nt < 8; ++nt) {
#pragma unroll
    for (int ds = 0; ds < 4; ++ds) {
      u16x8 bh = *(const u16x8*)(TBh + ((nt * 4 + ds) << 9) + lane * 8);
      u16x8 bl = *(const u16x8*)(TBl + ((nt * 4 + ds) << 9) + lane * 8);
#pragma unroll
      for (int mt = 0; mt < 2; ++mt) {
        acc[mt][nt] = __builtin_amdgcn_mfma_f32_16x16x32_bf16(asbf(ah[mt][ds]), asbf(bh), acc[mt][nt], 0, 0, 0);
        acc[mt][nt] = __builtin_amdgcn_mfma_f32_16x16x32_bf16(asbf(ah[mt][ds]), asbf(bl), acc[mt][nt], 0, 0, 0);
        acc[mt][nt] = __builtin_amdgcn_mfma_f32_16x16x32_bf16(asbf(al[mt][ds]), asbf(bh), acc[mt][nt], 0, 0, 0);
      }
    }
  }
  __syncthreads();

  ushort_t* OS = (ushort_t*)WoS;
#pragma unroll
  for (int mt = 0; mt < 2; ++mt)
#pragma unroll
    for (int nt = 0; nt < 8; ++nt)
#pragma unroll
      for (int reg = 0; reg < 4; ++reg)
        OS[(w * 32 + mt * 16 + g * 4 + reg) * 136 + nt * 16 + c] = f2b(acc[mt][nt][reg]);
  __syncthreads();

#pragma unroll
  for (int i = 0; i < 8; ++i) {
    int idx = tid + i * 256;
    int nn = idx >> 4, c8 = (idx & 15) * 8;
    *(u16x8*)&WT[(size_t)(n0 + nn) * 4096 + h * 128 + c8] = *(const u16x8*)&OS[nn * 136 + c8];
  }
}

// ---------------- bf16 MFMA GEMM (m97 structure): C = A x BT^T (final Wo GEMM) -------
__global__ __launch_bounds__(256) void gemm_bf16(const ushort_t* __restrict__ A,
                                                 const ushort_t* __restrict__ BT,
                                                 float* __restrict__ C,
                                                 int M, int N, int K, int qlayout)
{
  __shared__ __align__(16) ushort_t As[128 * 64];
  __shared__ __align__(16) ushort_t Bs[128 * 64];
  const int tid = threadIdx.x;
  const int bm = blockIdx.y * 128, bn = blockIdx.x * 128;
  const int lane = tid & 63, w = tid >> 6;
  const int c = lane & 15, g = lane >> 4;
  const int wm = (w >> 1) * 64, wn = (w & 1) * 64;
  f32x4 acc[4][4];
#pragma unroll
  for (int mt = 0; mt < 4; ++mt)
#pragma unroll
    for (int nt = 0; nt < 4; ++nt) acc[mt][nt] = (f32x4){0.f, 0.f, 0.f, 0.f};
  const int srow = tid >> 3;
  const int slot = (tid & 7) ^ (srow & 7);
  for (int k0 = 0; k0 < K; k0 += 64) {
    __syncthreads();
#pragma unroll
    for (int ii = 0; ii < 4; ++ii) {
      gload16(A  + (size_t)(bm + ii * 32 + srow) * K + k0 + slot * 8,
              (char*)As + w * 1024 + ii * 4096);
      gload16(BT + (size_t)(bn + ii * 32 + srow) * K + k0 + slot * 8,
              (char*)Bs + w * 1024 + ii * 4096);
    }
    __syncthreads();
#pragma unroll
    for (int ks = 0; ks < 2; ++ks) {
      bf16x8 av[4], bv[4];
#pragma unroll
      for (int mt = 0; mt < 4; ++mt)
        av[mt] = *(const bf16x8*)((const char*)As + (wm + mt * 16 + c) * 128 +
                                  (((ks * 4 + g) ^ (c & 7)) << 4));
#pragma unroll
      for (int nt = 0; nt < 4; ++nt)
        bv[nt] = *(const bf16x8*)((const char*)Bs + (wn + nt * 16 + c) * 128 +
                                  (((ks * 4 + g) ^ (c & 7)) << 4));
#pragma unroll
      for (int mt = 0; mt < 4; ++mt)
#pragma unroll
        for (int nt = 0; nt < 4; ++nt)
          acc[mt][nt] = __builtin_amdgcn_mfma_f32_16x16x32_bf16(av[mt], bv[nt], acc[mt][nt], 0, 0, 0);
    }
  }
#pragma unroll
  for (int mt = 0; mt < 4; ++mt)
#pragma unroll
    for (int nt = 0; nt < 4; ++nt)
#pragma unroll
      for (int reg = 0; reg < 4; ++reg) {
        int m = bm + wm + mt * 16 + g * 4 + reg;
        int n = bn + wn + nt * 16 + c;
        float v = acc[mt][nt][reg];
        if (qlayout) C[((size_t)(n >> 7) * S_ + m) * 128 + (n & 127)] = v;
        else         C[(size_t)m * N + n] = v;
      }
}

// ---------------- gemm_qkv: fused Wq GEMM (path 0) + Wk/Wv 3-pass GEMM (path 1) ------
// 1024 blocks alternating paths -> both GEMMs co-resident on every CU, each path's
// barrier/vmcnt stalls overlap the other's MFMA. Bodies identical to the two parents.
__global__ __launch_bounds__(256) void gemm_qkv(
    const ushort_t* __restrict__ Ahi, const ushort_t* __restrict__ Alo,
    const ushort_t* __restrict__ WqT,
    const ushort_t* __restrict__ KVh, const ushort_t* __restrict__ KVl,
    float* __restrict__ Cq, float* __restrict__ Ck, float* __restrict__ Cv)
{
  __shared__ __align__(16) char smem[49152];
  const int b = blockIdx.x;         // 0..1023
  const int path = b & 1;           // 0 = q, 1 = kv
  const int idx = b >> 1;           // 0..511
  const int tid = threadIdx.x;
  const int lane = tid & 63, w = tid >> 6;
  const int c = lane & 15, g = lane >> 4;
  const int srow = tid >> 3;
  const int slot = (tid & 7) ^ (srow & 7);
  const int K = DM_;

  if (path == 0) {
    ushort_t* As = (ushort_t*)smem;
    ushort_t* Bs = (ushort_t*)smem + 128 * 64;
    const int bn = (idx & 31) * 128, bm = (idx >> 5) * 128;
    const int wm = (w >> 1) * 64, wn = (w & 1) * 64;
    f32x4 acc[4][4];
#pragma unroll
    for (int mt = 0; mt < 4; ++mt)
#pragma unroll
      for (int nt = 0; nt < 4; ++nt) acc[mt][nt] = (f32x4){0.f, 0.f, 0.f, 0.f};
    for (int k0 = 0; k0 < K; k0 += 64) {
      __syncthreads();
#pragma unroll
      for (int ii = 0; ii < 4; ++ii) {
        gload16(Ahi + (size_t)(bm + ii * 32 + srow) * K + k0 + slot * 8,
                (char*)As + w * 1024 + ii * 4096);
        gload16(WqT + (size_t)(bn + ii * 32 + srow) * K + k0 + slot * 8,
                (char*)Bs + w * 1024 + ii * 4096);
      }
      __syncthreads();
#pragma unroll
      for (int ks = 0; ks < 2; ++ks) {
        bf16x8 av[4], bv[4];
#pragma unroll
        for (int mt = 0; mt < 4; ++mt)
          av[mt] = *(const bf16x8*)((const char*)As + (wm + mt * 16 + c) * 128 +
                                    (((ks * 4 + g) ^ (c & 7)) << 4));
#pragma unroll
        for (int nt = 0; nt < 4; ++nt)
          bv[nt] = *(const bf16x8*)((const char*)Bs + (wn + nt * 16 + c) * 128 +
                                    (((ks * 4 + g) ^ (c & 7)) << 4));
#pragma unroll
        for (int mt = 0; mt < 4; ++mt)
#pragma unroll
          for (int nt = 0; nt < 4; ++nt)
            acc[mt][nt] = __builtin_amdgcn_mfma_f32_16x16x32_bf16(av[mt], bv[nt], acc[mt][nt], 0, 0, 0);
      }
    }
#pragma unroll
    for (int mt = 0; mt < 4; ++mt)
#pragma unroll
      for (int nt = 0; nt < 4; ++nt)
#pragma unroll
        for (int reg = 0; reg < 4; ++reg) {
          int m = bm + wm + mt * 16 + g * 4 + reg;
          int n = bn + wn + nt * 16 + c;
          Cq[((size_t)(n >> 7) * S_ + m) * 128 + (n & 127)] = acc[mt][nt][reg];
        }
  } else {
    ushort_t* Ash = (ushort_t*)smem;
    ushort_t* Asl = Ash + 128 * 64;
    ushort_t* Bsh = Asl + 128 * 64;
    ushort_t* Bsl = Bsh + 64 * 64;
    const int bn = (idx & 31) * 64, bm = (idx >> 5) * 128;
    const int wm = w * 32;
    f32x4 acc[2][4];
#pragma unroll
    for (int mt = 0; mt < 2; ++mt)
#pragma unroll
      for (int nt = 0; nt < 4; ++nt) acc[mt][nt] = (f32x4){0.f, 0.f, 0.f, 0.f};
    for (int k0 = 0; k0 < K; k0 += 64) {
      __syncthreads();
#pragma unroll
      for (int ii = 0; ii < 4; ++ii) {
        const size_t ga = (size_t)(bm + ii * 32 + srow) * K + k0 + slot * 8;
        gload16(Ahi + ga, (char*)Ash + w * 1024 + ii * 4096);
        gload16(Alo + ga, (char*)Asl + w * 1024 + ii * 4096);
      }
#pragma unroll
      for (int ii = 0; ii < 2; ++ii) {
        const size_t gb = (size_t)(bn + ii * 32 + srow) * K + k0 + slot * 8;
        gload16(KVh + gb, (char*)Bsh + w * 1024 + ii * 4096);
        gload16(KVl + gb, (char*)Bsl + w * 1024 + ii * 4096);
      }
      __syncthreads();
#pragma unroll
      for (int ks = 0; ks < 2; ++ks) {
        bf16x8 ah[2], al[2], bh[4], bl[4];
#pragma unroll
        for (int mt = 0; mt < 2; ++mt) {
          int ro = (wm + mt * 16 + c) * 128;
          int so = ((ks * 4 + g) ^ (c & 7)) << 4;
          ah[mt] = *(const bf16x8*)((const char*)Ash + ro + so);
          al[mt] = *(const bf16x8*)((const char*)Asl + ro + so);
        }
#pragma unroll
        for (int nt = 0; nt < 4; ++nt) {
          int ro = (nt * 16 + c) * 128;
          int so = ((ks * 4 + g) ^ (c & 7)) << 4;
          bh[nt] = *(const bf16x8*)((const char*)Bsh + ro + so);
          bl[nt] = *(const bf16x8*)((const char*)Bsl + ro + so);
        }
#pragma unroll
        for (int mt = 0; mt < 2; ++mt)
#pragma unroll
          for (int nt = 0; nt < 4; ++nt) {
            acc[mt][nt] = __builtin_amdgcn_mfma_f32_16x16x32_bf16(ah[mt], bh[nt], acc[mt][nt], 0, 0, 0);
            acc[mt][nt] = __builtin_amdgcn_mfma_f32_16x16x32_bf16(ah[mt], bl[nt], acc[mt][nt], 0, 0, 0);
            acc[mt][nt] = __builtin_amdgcn_mfma_f32_16x16x32_bf16(al[mt], bh[nt], acc[mt][nt], 0, 0, 0);
          }
      }
    }
#pragma unroll
    for (int mt = 0; mt < 2; ++mt)
#pragma unroll
      for (int nt = 0; nt < 4; ++nt)
#pragma unroll
        for (int reg = 0; reg < 4; ++reg) {
          int m = bm + wm + mt * 16 + g * 4 + reg;
          int n = bn + nt * 16 + c;
          float v = acc[mt][nt][reg];
          if (n < 1024) Ck[((size_t)(n >> 7) * S_ + m) * 128 + (n & 127)] = v;
          else          Cv[((size_t)((n - 1024) >> 7) * S_ + m) * 128 + (n & 127)] = v;
        }
  }
}

// ---------------- tpost_all: merged q/k/v post (rope + @T + scale/quant + frag store) --
__global__ __launch_bounds__(256) void tpost_all(
    const float* __restrict__ qsrc, const float* __restrict__ ksrc,
    const float* __restrict__ vsrc,
    const ushort_t* __restrict__ tfH, const ushort_t* __restrict__ tfL,
    const float* __restrict__ cosT, const float* __restrict__ sinT,
    ushort_t* __restrict__ qfrag, ushort_t* __restrict__ kfrag,
    ushort_t* __restrict__ vfrag)
{
  const int b = blockIdx.x;        // 0..3071
  const float* src; const ushort_t *Thi, *Tlo; ushort_t* outp; int mode, blk;
  if (b < 2048)      { src = qsrc; Thi = tfH;             Tlo = tfL;             outp = qfrag; mode = 0; blk = b; }
  else if (b < 2560) { src = ksrc; Thi = tfH + 16384;     Tlo = tfL + 16384;     outp = kfrag; mode = 1; blk = b - 2048; }
  else               { src = vsrc; Thi = tfH + 2 * 16384; Tlo = tfL + 2 * 16384; outp = vfrag; mode = 2; blk = b - 2560; }

  const int tid = threadIdx.x;
  const int w = tid >> 6, lane = tid & 63;
  const int c = lane & 15, g = lane >> 4;

  __shared__ float raw_[32 * 132];
  __shared__ float rop_[32 * 132];
  __shared__ __align__(16) ushort_t vtile[32][136];

#pragma unroll
  for (int i = 0; i < 4; ++i) {
    int idx = tid + i * 256;
    int row = idx >> 5, c4 = (idx & 31) * 4;
    *(float4*)&raw_[row * 132 + c4] =
        *(const float4*)&src[(size_t)(blk * 32 + row) * 128 + c4];
  }
  __syncthreads();

  {
    const int r = tid >> 3, co = (tid & 7) * 16;
    if (mode <= 1) {
      const int s = (blk & 63) * 32 + r;
      const float* ct = cosT + (size_t)s * 64;
      const float* st = sinT + (size_t)s * 64;
#pragma unroll
      for (int j = 0; j < 16; ++j) {
        int cc = co + j, i2 = cc & 63;
        float x = raw_[r * 132 + cc];
        float other = (cc < 64) ? raw_[r * 132 + cc + 64] : raw_[r * 132 + cc - 64];
        rop_[r * 132 + cc] = (cc < 64) ? (x * ct[i2] - other * st[i2])
                                       : (x * ct[i2] + other * st[i2]);
      }
    } else {
#pragma unroll
      for (int j = 0; j < 16; ++j) {
        int cc = co + j;
        rop_[r * 132 + cc] = raw_[r * 132 + cc];
      }
    }
  }
  __syncthreads();

  u16x8 ahu[2][4], alu[2][4];
#pragma unroll
  for (int mt = 0; mt < 2; ++mt)
#pragma unroll
    for (int ds = 0; ds < 4; ++ds) {
      u16x8 th, tl;
#pragma unroll
      for (int j = 0; j < 8; ++j) {
        float x = rop_[(mt * 16 + c) * 132 + ds * 32 + g * 8 + j];
        ushort_t hb = f2b(x);
        th[j] = hb;
        tl[j] = f2b(x - b2f(hb));
      }
      ahu[mt][ds] = th;
      alu[mt][ds] = tl;
    }

  f32x4 acc[2][2];
#pragma unroll
  for (int mt = 0; mt < 2; ++mt)
#pragma unroll
    for (int nl = 0; nl < 2; ++nl) acc[mt][nl] = (f32x4){0.f, 0.f, 0.f, 0.f};
#pragma unroll
  for (int nl = 0; nl < 2; ++nl) {
    const int nt = w * 2 + nl;
    u16x8 bh[4], bl[4];
#pragma unroll
    for (int ds = 0; ds < 4; ++ds) {
      bh[ds] = *(const u16x8*)(Thi + ((nt * 4 + ds) << 9) + lane * 8);
      bl[ds] = *(const u16x8*)(Tlo + ((nt * 4 + ds) << 9) + lane * 8);
    }
#pragma unroll
    for (int mt = 0; mt < 2; ++mt)
#pragma unroll
      for (int ds = 0; ds < 4; ++ds) {
        acc[mt][nl] = __builtin_amdgcn_mfma_f32_16x16x32_bf16(asbf(ahu[mt][ds]), asbf(bh[ds]), acc[mt][nl], 0, 0, 0);
        acc[mt][nl] = __builtin_amdgcn_mfma_f32_16x16x32_bf16(asbf(ahu[mt][ds]), asbf(bl[ds]), acc[mt][nl], 0, 0, 0);
        acc[mt][nl] = __builtin_amdgcn_mfma_f32_16x16x32_bf16(asbf(alu[mt][ds]), asbf(bh[ds]), acc[mt][nl], 0, 0, 0);
      }
  }
  __syncthreads();

#pragma unroll
  for (int mt = 0; mt < 2; ++mt)
#pragma unroll
    for (int nl = 0; nl < 2; ++nl)
#pragma unroll
      for (int reg = 0; reg < 4; ++reg)
        raw_[(mt * 16 + g * 4 + reg) * 132 + (w * 2 + nl) * 16 + c] = acc[mt][nl][reg];
  __syncthreads();

  const int r = tid >> 3, co = (tid & 7) * 16;
  float vals[16];
#pragma unroll
  for (int j = 0; j < 16; ++j) vals[j] = raw_[r * 132 + co + j];

  if (mode == 0) {
#pragma unroll
    for (int j = 0; j < 16; ++j) vals[j] *= 0.08838834764831845f;
  } else {
    float m = 0.0f;
#pragma unroll
    for (int j = 0; j < 16; ++j) m = fmaxf(m, fabsf(vals[j]));
    m = fmaxf(m, __shfl_xor(m, 1));
    m = fmaxf(m, __shfl_xor(m, 2));
    m = fmaxf(m, __shfl_xor(m, 4));
    const float sc = fmaxf(m * (1.0f / 7.0f), 1e-8f);
#pragma unroll
    for (int j = 0; j < 16; ++j) {
      float qv = rintf(vals[j] / sc);
      qv = fminf(7.0f, fmaxf(-7.0f, qv));
      vals[j] = qv * sc;
    }
  }

  if (mode <= 1) {
    const size_t chunkbase = ((size_t)blk << 13) +
                             ((size_t)((r >> 4) * 4 + (co >> 5)) << 10);
    const int lane0 = ((co >> 3) & 3) * 16 + (r & 15);
    const int lane1 = (((co + 8) >> 3) & 3) * 16 + (r & 15);
    u16x8 o0, o1;
#pragma unroll
    for (int j = 0; j < 8; ++j) { o0[j] = f2b(vals[j]); o1[j] = f2b(vals[j + 8]); }
    *(u16x8*)((char*)outp + chunkbase + lane0 * 16) = o0;
    *(u16x8*)((char*)outp + chunkbase + lane1 * 16) = o1;
  } else {
#pragma unroll
    for (int j = 0; j < 16; ++j) vtile[r][co + j] = f2b(vals[j]);
    __syncthreads();
#pragma unroll
    for (int i = 0; i < 2; ++i) {
      int id = tid + i * 256;
      int dt = id >> 6, ln = id & 63;
      int gg = ln >> 4, cc = ln & 15;
      u16x8 o;
#pragma unroll
      for (int j = 0; j < 8; ++j) o[j] = vtile[gg * 8 + j][dt * 16 + cc];
      *(u16x8*)(outp + (((size_t)blk) << 12) + (dt << 9) + ln * 8) = o;
    }
  }
}

// ---------------- MFMA flash attention v6 (round-10 proven body) ----------------
__global__ __launch_bounds__(256) void attn_mfma6(
    const ushort_t* __restrict__ qf_,
    const ushort_t* __restrict__ kf_,
    const ushort_t* __restrict__ vf_,
    ushort_t* __restrict__ o16)
{
  const int lid = blockIdx.x;
  const int xcd = lid & 7;
  const int idx = lid >> 3;
  const int h   = xcd * 4 + (idx & 3);
  const int kb  = idx >> 2;
  const int kvh = xcd;

  const int tid = threadIdx.x;
  const int w    = tid >> 6;
  const int lane = tid & 63;
  const int c = lane & 15, g = lane >> 4;
  const int qt = (w < 2) ? (2 * kb + w) : (60 - 2 * kb + w);

  __shared__ __align__(16) ushort_t Ps[4][2][16][40];

  const float LOG2E = 1.44269504f;
  const float MBIAS = 28.8539008f;    // p = 2^(s*log2e - MBIAS) = e^(s-20)

  const char* qtile = (const char*)qf_ + (((size_t)(h * 64 + qt)) << 13);
  bf16x8 qf[2][4];
#pragma unroll
  for (int mt = 0; mt < 2; ++mt)
#pragma unroll
    for (int ds = 0; ds < 4; ++ds)
      qf[mt][ds] = *(const bf16x8*)(qtile + ((mt * 4 + ds) << 10) + lane * 16);

  bf16x8 ones;
#pragma unroll
  for (int j = 0; j < 8; ++j) ones[j] = (__bf16)1.0f;

  f32x4 oa[2][8];
#pragma unroll
  for (int mt = 0; mt < 2; ++mt)
#pragma unroll
    for (int dt = 0; dt < 8; ++dt) oa[mt][dt] = (f32x4){0.f, 0.f, 0.f, 0.f};
  f32x4 la[2];
  la[0] = (f32x4){0.f, 0.f, 0.f, 0.f};
  la[1] = (f32x4){0.f, 0.f, 0.f, 0.f};

  const char* kbase = (const char*)kf_ + (((size_t)kvh * 64) << 13);
  const char* vbase = (const char*)vf_ + (((size_t)kvh * 64) << 13);

  for (int kt = 0; kt <= qt; ++kt) {
    const char* ktile = kbase + ((size_t)kt << 13);
    const char* vtile = vbase + ((size_t)kt << 13);
    bf16x8 kc[2][4], vc[8];
#pragma unroll
    for (int nt = 0; nt < 2; ++nt)
#pragma unroll
      for (int ds = 0; ds < 4; ++ds)
        kc[nt][ds] = *(const bf16x8*)(ktile + ((nt * 4 + ds) << 10) + lane * 16);
#pragma unroll
    for (int dt = 0; dt < 8; ++dt)
      vc[dt] = *(const bf16x8*)(vtile + (dt << 10) + lane * 16);

    f32x4 sc[2][2];
#pragma unroll
    for (int mt = 0; mt < 2; ++mt)
#pragma unroll
      for (int nt = 0; nt < 2; ++nt) sc[mt][nt] = (f32x4){0.f, 0.f, 0.f, 0.f};
    __builtin_amdgcn_s_setprio(1);
#pragma unroll
    for (int ds = 0; ds < 4; ++ds) {
      sc[0][0] = __builtin_amdgcn_mfma_f32_16x16x32_bf16(qf[0][ds], kc[0][ds], sc[0][0], 0, 0, 0);
      sc[0][1] = __builtin_amdgcn_mfma_f32_16x16x32_bf16(qf[0][ds], kc[1][ds], sc[0][1], 0, 0, 0);
      sc[1][0] = __builtin_amdgcn_mfma_f32_16x16x32_bf16(qf[1][ds], kc[0][ds], sc[1][0], 0, 0, 0);
      sc[1][1] = __builtin_amdgcn_mfma_f32_16x16x32_bf16(qf[1][ds], kc[1][ds], sc[1][1], 0, 0, 0);
    }
    __builtin_amdgcn_s_setprio(0);

#pragma unroll
    for (int mt = 0; mt < 2; ++mt) {
#pragma unroll
      for (int reg = 0; reg < 4; ++reg) {
        float s0 = sc[mt][0][reg], s1 = sc[mt][1][reg];
        if (kt == qt) {
          int qrl = mt * 16 + g * 4 + reg;
          if (c > qrl)      s0 = -INFINITY;
          if (16 + c > qrl) s1 = -INFINITY;
        }
        float p0 = exp2f(s0 * LOG2E - MBIAS);
        float p1 = exp2f(s1 * LOG2E - MBIAS);
        Ps[w][mt][g * 4 + reg][c]      = f2b(p0);
        Ps[w][mt][g * 4 + reg][16 + c] = f2b(p1);
      }
    }

    bf16x8 pa0 = *reinterpret_cast<const bf16x8*>(&Ps[w][0][c][g * 8]);
    bf16x8 pa1 = *reinterpret_cast<const bf16x8*>(&Ps[w][1][c][g * 8]);
    __builtin_amdgcn_s_setprio(1);
#pragma unroll
    for (int dt = 0; dt < 8; ++dt) {
      oa[0][dt] = __builtin_amdgcn_mfma_f32_16x16x32_bf16(pa0, vc[dt], oa[0][dt], 0, 0, 0);
      oa[1][dt] = __builtin_amdgcn_mfma_f32_16x16x32_bf16(pa1, vc[dt], oa[1][dt], 0, 0, 0);
    }
    la[0] = __builtin_amdgcn_mfma_f32_16x16x32_bf16(pa0, ones, la[0], 0, 0, 0);
    la[1] = __builtin_amdgcn_mfma_f32_16x16x32_bf16(pa1, ones, la[1], 0, 0, 0);
    __builtin_amdgcn_s_setprio(0);
  }

#pragma unroll
  for (int mt = 0; mt < 2; ++mt)
#pragma unroll
    for (int reg = 0; reg < 4; ++reg) {
      float li = 1.0f / la[mt][reg];
      int srow = qt * 32 + mt * 16 + g * 4 + reg;
      ushort_t* orow = o16 + (size_t)srow * DM_ + h * 128;
#pragma unroll
      for (int dt = 0; dt < 8; ++dt)
        orow[dt * 16 + c] = f2b(oa[mt][dt][reg] * li);
    }
}

extern "C" void kernel_launch(void* const* d_in, const int* in_sizes, int n_in,
                              void* d_out, int out_size, void* d_ws, size_t ws_size,
                              hipStream_t stream)
{
  (void)in_sizes; (void)n_in; (void)out_size; (void)ws_size;
  const float* hidden = (const float*)d_in[0];
  const int*   pos    = (const int*)d_in[2];
  const float* lnL    = (const float*)d_in[3];
  const float* lnR    = (const float*)d_in[4];
  const float* Wq     = (const float*)d_in[5];
  const float* Wk     = (const float*)d_in[6];
  const float* Wv     = (const float*)d_in[7];
  const float* Wo     = (const float*)d_in[8];
  const float* Tk     = (const float*)d_in[9];
  const float* Tv     = (const float*)d_in[10];
  float* out = (float*)d_out;

  float* ws   = (float*)d_ws;
  float* hbuf = ws;                                    // 32MB region, subdivided below
  float* kbuf = hbuf + (size_t)S_ * DM_;               // 8MB fp32 K pre-quant [kvh][s][d]
  float* vbuf = kbuf + (size_t)S_ * KVH_ * HD_;        // 8MB fp32 V pre-quant [kvh][s][d]
  float* Tkit = vbuf + (size_t)S_ * KVH_ * HD_;        // inv(Tk)^T
  float* TvI  = Tkit + 128 * 128;                      // inv(Tv)
  float* cosT = TvI + 128 * 128;                       // S*64
  float* sinT = cosT + (size_t)S_ * 64;                // S*64
  ushort_t* hb16 = (ushort_t*)(sinT + (size_t)S_ * 64);   // 16MB bf16 (LN hi; later attn out)
  ushort_t* WT   = hb16 + (size_t)S_ * DM_;               // 32MB bf16 (WqT | KV hi+lo | WoT')
  float* nb      = (float*)(WT + (size_t)DM_ * DM_);      // Newton: 6 x 16384 floats
  ushort_t* tfH  = (ushort_t*)(nb + 6 * 16384);           // 4 x 32KB B-frag hi
  ushort_t* tfL  = tfH + 4 * 16384;                       // 4 x 32KB B-frag lo
  ushort_t* RBh  = tfL + 4 * 16384;                       // 8KB each: R/L 64x64 frag packs
  ushort_t* RBl  = RBh + 4096;
  ushort_t* LBh  = RBl + 4096;
  ushort_t* LBl  = LBh + 4096;

  // subdivision of the 32MB hbuf region:
  char* hbytes = (char*)hbuf;
  ushort_t* hlo16 = (ushort_t*)hbytes;                    // [0,16MB)  LN lo (dead after gemm_qkv)
  ushort_t* qfrag = (ushort_t*)hbytes;                    // [0,16MB)  q fragment tiles
  ushort_t* kfrag = (ushort_t*)(hbytes + (16u << 20));    // [16,20MB) k fragment tiles
  ushort_t* vfrag = (ushort_t*)(hbytes + (20u << 20));    // [20,24MB) v fragment tiles

  ushort_t* WTkh = WT;
  ushort_t* WTkl = WT + (size_t)2048 * DM_;
  ushort_t* WqT  = WT + (size_t)2048 * DM_ * 2;           // NOTE: fits? WT is 32MB = 4096*4096*2B
  // WT layout: rows [0,2048) hi | [2048,4096) lo used by KV; WqT needs its own 32MB —
  // reuse: place WqT in the upper half? 4096*4096 ushort = 32MB total. KV hi+lo =
  // 2048*4096*2 = 16MB + 16MB = 32MB. Conflict! Keep WqT in WT rows as before and
  // KV in the same buffer is NOT possible concurrently. Give WqT the vfrag+ region:
  // it must persist only through gemm_qkv, before tpost writes frags. Use a dedicated
  // region after LBl instead (32MB more of workspace).
  ushort_t* WqTbuf = LBl + 4096;                          // 32MB bf16 [4096][4096]

  float* Xk = nb,              *Xv = nb + 16384;
  float* Yk = nb + 2 * 16384,  *Yv = nb + 3 * 16384;
  float* Xk2 = nb + 4 * 16384, *Xv2 = nb + 5 * 16384;

  float* qbuf = out;  // d_out as q scratch [H][S][128] fp32

  // ---- Newton inverse (4 iters): Tkit = inv(Tk)^T, TvI = inv(Tv)
  newton_init<<<dim3(2, 16), 1024, 0, stream>>>(Tk, Tv, Xk, Xv);
  for (int it = 0; it < 4; ++it) {
    nmm<<<dim3(4, 2), 256, 0, stream>>>(Tk, Xk, Yk, 0, Tv, Xv, Yv, 0, 0);
    const int last = (it == 3);
    float* ok = last ? Tkit : Xk2;
    float* ov = last ? TvI  : Xv2;
    nmm<<<dim3(4, 2), 256, 0, stream>>>(Xk, Yk, ok, last ? 1 : 0, Xv, Yv, ov, 0, 1);
    float* t;
    t = Xk; Xk = Xk2; Xk2 = t;
    t = Xv; Xv = Xv2; Xv2 = t;
  }
  prep_all<<<6, 256, 0, stream>>>(Tkit, Tk, Tv, TvI, lnR, lnL,
                                  tfH, tfL, RBh, RBl, LBh, LBl);

  trans_all<<<6144, 256, 0, stream>>>(Wq, Wk, Wv, WqTbuf, WTkh, WTkl);
  lnrope<<<1024, 256, 0, stream>>>(hidden, pos, RBh, RBl, LBh, LBl,
                                   hb16, hlo16, cosT, sinT);

  gemm_qkv<<<1024, 256, 0, stream>>>(hb16, hlo16, WqTbuf, WTkh, WTkl,
                                     qbuf, kbuf, vbuf);

  tpost_all<<<3072, 256, 0, stream>>>(qbuf, kbuf, vbuf, tfH, tfL,
                                      cosT, sinT, qfrag, kfrag, vfrag);

  attn_mfma6<<<dim3(S_ / 128 * H_), 256, 0, stream>>>(qfrag, kfrag, vfrag, hb16);

  wfold3<<<dim3(DM_ / 128, H_), 256, 0, stream>>>(Wo, tfH + 3 * 16384, tfL + 3 * 16384, WT);
  gemm_bf16<<<dim3(DM_ / 128, S_ / 128), 256, 0, stream>>>(hb16, WT, out, S_, DM_, DM_, 0);
}

// Round 18
// 567.513 us; speedup vs baseline: 1.0686x; 1.0023x over previous
//
#include <hip/hip_runtime.h>
#include <math.h>

#define S_    2048
#define DM_   4096
#define H_    32
#define KVH_  8
#define HD_   128

typedef __bf16 bf16x8 __attribute__((ext_vector_type(8)));
typedef float  f32x4  __attribute__((ext_vector_type(4)));
typedef unsigned short u16x8 __attribute__((ext_vector_type(8)));
typedef unsigned short ushort_t;

// float -> bf16 bits, round-to-nearest-even
__device__ __forceinline__ ushort_t f2b(float f) {
  unsigned int u = __float_as_uint(f);
  unsigned int r = (u + 0x7fffu + ((u >> 16) & 1u)) >> 16;
  return (ushort_t)r;
}
__device__ __forceinline__ float b2f(ushort_t h) {
  return __uint_as_float(((unsigned int)h) << 16);
}
__device__ __forceinline__ bf16x8 asbf(u16x8 v) {
  return __builtin_bit_cast(bf16x8, v);
}

// async global->LDS, 16 bytes per lane
__device__ __forceinline__ void gload16(const void* g, void* l) {
  __builtin_amdgcn_global_load_lds(
      (const __attribute__((address_space(1))) void*)g,
      (__attribute__((address_space(3))) void*)(unsigned int)(unsigned long long)l,
      16, 0, 0);
}

// ---------------- Newton inverse: X0 = 2I - A (both matrices) ----------------
__global__ void newton_init(const float* __restrict__ A0, const float* __restrict__ A1,
                            float* __restrict__ X0, float* __restrict__ X1)
{
  const float* A = blockIdx.x ? A1 : A0;
  float*       X = blockIdx.x ? X1 : X0;
  const int i = blockIdx.y * 1024 + threadIdx.x;
  const int r = i >> 7, c = i & 127;
  X[i] = ((r == c) ? 2.0f : 0.0f) - A[i];
}

// ---------------- 128x128 fp32 matmul, dual-matrix, Newton-step epilogue --------------
__global__ __launch_bounds__(256) void nmm(
    const float* __restrict__ A0, const float* __restrict__ B0, float* __restrict__ C0, int tr0,
    const float* __restrict__ A1, const float* __restrict__ B1, float* __restrict__ C1, int tr1,
    int update)
{
  const float* A = blockIdx.y ? A1 : A0;
  const float* B = blockIdx.y ? B1 : B0;
  float*       C = blockIdx.y ? C1 : C0;
  const int tr   = blockIdx.y ? tr1 : tr0;
  const int m0   = blockIdx.x * 32;
  const int tid  = threadIdx.x;

  __shared__ float Bs[128][132];
  __shared__ float As[32][132];

#pragma unroll
  for (int i = 0; i < 16; ++i) {
    int idx = tid + i * 256;
    int row = idx >> 5, c4 = (idx & 31) * 4;
    *(float4*)&Bs[row][c4] = *(const float4*)&B[row * 128 + c4];
  }
#pragma unroll
  for (int i = 0; i < 4; ++i) {
    int idx = tid + i * 256;
    int row = idx >> 5, c4 = (idx & 31) * 4;
    *(float4*)&As[row][c4] = *(const float4*)&A[(m0 + row) * 128 + c4];
  }
  __syncthreads();

  const int rloc = tid >> 3;
  const int c0   = (tid & 7) * 16;
  float acc[16];
#pragma unroll
  for (int j = 0; j < 16; ++j) acc[j] = 0.0f;
  for (int k = 0; k < 128; ++k) {
    float a = As[rloc][k];
#pragma unroll
    for (int j = 0; j < 16; j += 4) {
      float4 bv = *(const float4*)&Bs[k][c0 + j];
      acc[j + 0] += a * bv.x; acc[j + 1] += a * bv.y;
      acc[j + 2] += a * bv.z; acc[j + 3] += a * bv.w;
    }
  }
#pragma unroll
  for (int j = 0; j < 16; ++j) {
    float v = update ? (2.0f * As[rloc][c0 + j] - acc[j]) : acc[j];
    if (tr) C[(c0 + j) * 128 + (m0 + rloc)] = v;
    else    C[(m0 + rloc) * 128 + c0 + j]   = v;
  }
}

// ---------------- prep_all: fragment packs for T matrices + LN R/L -------------------
__global__ void prep_all(const float* __restrict__ Tkit, const float* __restrict__ Tk,
                         const float* __restrict__ Tv,   const float* __restrict__ TvI,
                         const float* __restrict__ lnR,  const float* __restrict__ lnL,
                         ushort_t* __restrict__ Fhi, ushort_t* __restrict__ Flo,
                         ushort_t* __restrict__ RBh, ushort_t* __restrict__ RBl,
                         ushort_t* __restrict__ LBh, ushort_t* __restrict__ LBl)
{
  const int mat = blockIdx.x;   // 0..5
  const int t   = threadIdx.x;  // 256
  if (mat < 4) {
    const float* src = (mat == 0) ? Tkit : ((mat == 1) ? Tk : ((mat == 2) ? Tv : TvI));
    const int tr = (mat == 3);
    ushort_t* hi = Fhi + mat * 16384;
    ushort_t* lo = Flo + mat * 16384;
    for (int ch = 0; ch < 32; ++ch) {
      int nt = ch >> 2, ds = ch & 3;
#pragma unroll
      for (int i = 0; i < 2; ++i) {
        int idx = t + i * 256;            // 0..511
        int ln = idx >> 3, j = idx & 7;
        int cc = ln & 15, gg = ln >> 4;
        int d = ds * 32 + gg * 8 + j, n = nt * 16 + cc;
        float x = tr ? src[n * 128 + d] : src[d * 128 + n];
        ushort_t hb = f2b(x);
        hi[(ch << 9) + idx] = hb;
        lo[(ch << 9) + idx] = f2b(x - b2f(hb));
      }
    }
  } else {
    const float* src = (mat == 4) ? lnR : lnL;
    ushort_t* hp = (mat == 4) ? RBh : LBh;
    ushort_t* lp = (mat == 4) ? RBl : LBl;
    for (int ch = 0; ch < 8; ++ch) {
      int nt = ch >> 1, ds = ch & 1;
#pragma unroll
      for (int i = 0; i < 2; ++i) {
        int idx = t + i * 256;
        int ln = idx >> 3, j = idx & 7;
        int cc = ln & 15, gg = ln >> 4;
        float x = src[(ds * 32 + gg * 8 + j) * 64 + nt * 16 + cc];
        ushort_t hb = f2b(x);
        hp[(ch << 9) + idx] = hb;
        lp[(ch << 9) + idx] = f2b(x - b2f(hb));
      }
    }
  }
}

// ---------------- trans_all: Wq transpose (hi) + Wk/Wv transpose hi/lo ---------------
__global__ void trans_all(const float* __restrict__ Wq, const float* __restrict__ Wk,
                          const float* __restrict__ Wv,
                          ushort_t* __restrict__ WT,
                          ushort_t* __restrict__ WThi, ushort_t* __restrict__ WTlo)
{
  const int b = blockIdx.x;       // 0..6143
  const int tid = threadIdx.x;
  __shared__ ushort_t th[64][68];
  __shared__ ushort_t tl[64][68];
  if (b < 4096) {
    const int n0 = (b & 63) * 64, k0 = (b >> 6) * 64;
    for (int idx = tid; idx < 4096; idx += 256) {
      int rr = idx >> 6, cc = idx & 63;
      th[cc][rr] = f2b(Wq[(size_t)(k0 + rr) * DM_ + n0 + cc]);
    }
    __syncthreads();
    for (int idx = tid; idx < 4096; idx += 256) {
      int rr = idx >> 6, cc = idx & 63;
      WT[(size_t)(n0 + rr) * DM_ + k0 + cc] = th[rr][cc];
    }
  } else {
    const int b2 = b - 4096;          // 0..2047
    const int which = b2 >> 10;       // 0 Wk, 1 Wv
    const int b3 = b2 & 1023;
    const float* W = which ? Wv : Wk;
    const int rowoff = which ? 1024 : 0;
    const int n0 = (b3 & 15) * 64, k0 = (b3 >> 4) * 64;
    for (int idx = tid; idx < 4096; idx += 256) {
      int rr = idx >> 6, cc = idx & 63;
      float x = W[(size_t)(k0 + rr) * 1024 + n0 + cc];
      ushort_t h = f2b(x);
      th[cc][rr] = h;
      tl[cc][rr] = f2b(x - b2f(h));
    }
    __syncthreads();
    for (int idx = tid; idx < 4096; idx += 256) {
      int rr = idx >> 6, cc = idx & 63;
      size_t o = (size_t)(rowoff + n0 + rr) * DM_ + k0 + cc;
      WThi[o] = th[rr][cc];
      WTlo[o] = tl[rr][cc];
    }
  }
}

// ---------------- lnrope: ln3 (blocks 0..511) + rope table (blocks 512..1023) --------
__global__ __launch_bounds__(256) void lnrope(
    const float* __restrict__ hid, const int* __restrict__ pos,
    const ushort_t* __restrict__ RBh, const ushort_t* __restrict__ RBl,
    const ushort_t* __restrict__ LBh, const ushort_t* __restrict__ LBl,
    ushort_t* __restrict__ hb16, ushort_t* __restrict__ hlo16,
    float* __restrict__ cosT, float* __restrict__ sinT)
{
  __shared__ float Hs[4][64 * 68];
  const int bid = blockIdx.x;
  const int tid = threadIdx.x;

  if (bid >= 512) {
    const int s = (bid - 512) * 4 + (tid >> 6);
    const int i = tid & 63;
    float invf = 1.0f / (float)pow(10000.0, (double)i * (1.0 / 64.0));
    float ang  = (float)pos[s] * invf;
    cosT[s * 64 + i] = cosf(ang);
    sinT[s * 64 + i] = sinf(ang);
    return;
  }

  const int blk = bid;
  const int w = tid >> 6, lane = tid & 63;
  const int c = lane & 15, g = lane >> 4;

#pragma unroll
  for (int i = 0; i < 16; ++i) {
    int idx = tid + i * 256;
    int t = idx >> 10, e = idx & 1023;
    int l = e >> 4, r4 = (e & 15) * 4;
    *(float4*)&Hs[t][l * 68 + r4] =
        *(const float4*)&hid[((size_t)(blk * 4 + t)) * 4096 + l * 64 + r4];
  }
  __syncthreads();

  float* Hw = Hs[w];

  u16x8 ah[4][2], al[4][2];
#pragma unroll
  for (int mt = 0; mt < 4; ++mt)
#pragma unroll
    for (int ds = 0; ds < 2; ++ds) {
      u16x8 th, tl;
#pragma unroll
      for (int j = 0; j < 8; ++j) {
        float x = Hw[(mt * 16 + c) * 68 + ds * 32 + g * 8 + j];
        ushort_t hb = f2b(x); th[j] = hb; tl[j] = f2b(x - b2f(hb));
      }
      ah[mt][ds] = th; al[mt][ds] = tl;
    }

  f32x4 acc[4][4];
#pragma unroll
  for (int mt = 0; mt < 4; ++mt)
#pragma unroll
    for (int nt = 0; nt < 4; ++nt) acc[mt][nt] = (f32x4){0.f, 0.f, 0.f, 0.f};
#pragma unroll
  for (int nt = 0; nt < 4; ++nt) {
    u16x8 bh[2], bl[2];
#pragma unroll
    for (int ds = 0; ds < 2; ++ds) {
      bh[ds] = *(const u16x8*)(RBh + ((nt * 2 + ds) << 9) + lane * 8);
      bl[ds] = *(const u16x8*)(RBl + ((nt * 2 + ds) << 9) + lane * 8);
    }
#pragma unroll
    for (int mt = 0; mt < 4; ++mt)
#pragma unroll
      for (int ds = 0; ds < 2; ++ds) {
        acc[mt][nt] = __builtin_amdgcn_mfma_f32_16x16x32_bf16(asbf(ah[mt][ds]), asbf(bh[ds]), acc[mt][nt], 0, 0, 0);
        acc[mt][nt] = __builtin_amdgcn_mfma_f32_16x16x32_bf16(asbf(ah[mt][ds]), asbf(bl[ds]), acc[mt][nt], 0, 0, 0);
        acc[mt][nt] = __builtin_amdgcn_mfma_f32_16x16x32_bf16(asbf(al[mt][ds]), asbf(bh[ds]), acc[mt][nt], 0, 0, 0);
      }
  }

#pragma unroll
  for (int mt = 0; mt < 4; ++mt)
#pragma unroll
    for (int nt = 0; nt < 4; ++nt)
#pragma unroll
      for (int reg = 0; reg < 4; ++reg)
        Hw[(mt * 16 + g * 4 + reg) * 68 + nt * 16 + c] = acc[mt][nt][reg];

  u16x8 a2h[4][2], a2l[4][2];
#pragma unroll
  for (int mt = 0; mt < 4; ++mt)
#pragma unroll
    for (int ds = 0; ds < 2; ++ds) {
      a2h[mt][ds] = *(const u16x8*)(LBh + ((mt * 2 + ds) << 9) + lane * 8);
      a2l[mt][ds] = *(const u16x8*)(LBl + ((mt * 2 + ds) << 9) + lane * 8);
    }
  f32x4 acc2[4][4];
#pragma unroll
  for (int mt = 0; mt < 4; ++mt)
#pragma unroll
    for (int nt = 0; nt < 4; ++nt) acc2[mt][nt] = (f32x4){0.f, 0.f, 0.f, 0.f};
#pragma unroll
  for (int nt = 0; nt < 4; ++nt) {
#pragma unroll
    for (int ds = 0; ds < 2; ++ds) {
      u16x8 bh, bl;
#pragma unroll
      for (int j = 0; j < 8; ++j) {
        float x = Hw[(ds * 32 + g * 8 + j) * 68 + nt * 16 + c];
        ushort_t hb = f2b(x); bh[j] = hb; bl[j] = f2b(x - b2f(hb));
      }
#pragma unroll
      for (int mt = 0; mt < 4; ++mt) {
        acc2[mt][nt] = __builtin_amdgcn_mfma_f32_16x16x32_bf16(asbf(a2h[mt][ds]), asbf(bh), acc2[mt][nt], 0, 0, 0);
        acc2[mt][nt] = __builtin_amdgcn_mfma_f32_16x16x32_bf16(asbf(a2h[mt][ds]), asbf(bl), acc2[mt][nt], 0, 0, 0);
        acc2[mt][nt] = __builtin_amdgcn_mfma_f32_16x16x32_bf16(asbf(a2l[mt][ds]), asbf(bh), acc2[mt][nt], 0, 0, 0);
      }
    }
  }

  ushort_t* hp = (ushort_t*)Hw;       // hi plane [64][64]; lo plane at +4096
#pragma unroll
  for (int mt = 0; mt < 4; ++mt)
#pragma unroll
    for (int nt = 0; nt < 4; ++nt)
#pragma unroll
      for (int reg = 0; reg < 4; ++reg) {
        int a = mt * 16 + g * 4 + reg, cc2 = nt * 16 + c;
        float v = acc2[mt][nt][reg];
        ushort_t hb = f2b(v);
        hp[a * 64 + cc2] = hb;
        hp[4096 + a * 64 + cc2] = f2b(v - b2f(hb));
      }

  const size_t sbase = ((size_t)(blk * 4 + w)) * 4096;
#pragma unroll
  for (int i = 0; i < 8; ++i) {
    int idx = i * 64 + lane;
    int row = idx >> 3, c8 = (idx & 7) * 8;
    *(u16x8*)&hb16[sbase + row * 64 + c8]  = *(const u16x8*)&hp[row * 64 + c8];
    *(u16x8*)&hlo16[sbase + row * 64 + c8] = *(const u16x8*)&hp[4096 + row * 64 + c8];
  }
}

// ---------------- wfold3: MFMA hi/lo 3-pass fold of TvI into Wo ----------------
__global__ __launch_bounds__(256) void wfold3(
    const float* __restrict__ Wo,
    const ushort_t* __restrict__ TBh, const ushort_t* __restrict__ TBl,
    ushort_t* __restrict__ WT)
{
  const int n0 = blockIdx.x * 128;
  const int h  = blockIdx.y;
  const int tid = threadIdx.x;
  const int w = tid >> 6, lane = tid & 63;
  const int c = lane & 15, g = lane >> 4;

  __shared__ float WoS[128 * 132];

#pragma unroll
  for (int i = 0; i < 16; ++i) {
    int idx = tid + i * 256;
    int e = idx >> 5, n4 = (idx & 31) * 4;
    *(float4*)&WoS[e * 132 + n4] =
        *(const float4*)&Wo[(size_t)(h * 128 + e) * 4096 + n0 + n4];
  }
  __syncthreads();

  u16x8 ah[2][4], al[2][4];
#pragma unroll
  for (int mt = 0; mt < 2; ++mt)
#pragma unroll
    for (int ds = 0; ds < 4; ++ds) {
      u16x8 th, tl;
#pragma unroll
      for (int j = 0; j < 8; ++j) {
        float x = WoS[(ds * 32 + g * 8 + j) * 132 + w * 32 + mt * 16 + c];
        ushort_t hb = f2b(x); th[j] = hb; tl[j] = f2b(x - b2f(hb));
      }
      ah[mt][ds] = th; al[mt][ds] = tl;
    }

  f32x4 acc[2][8];
#pragma unroll
  for (int mt = 0; mt < 2; ++mt)
#pragma unroll
    for (int nt = 0; nt < 8; ++nt) acc[mt][nt] = (f32x4){0.f, 0.f, 0.f, 0.f};
#pragma unroll
  for (int nt = 0; nt < 8; ++nt) {
#pragma unroll
    for (int ds = 0; ds < 4; ++ds) {
      u16x8 bh = *(const u16x8*)(TBh + ((nt * 4 + ds) << 9) + lane * 8);
      u16x8 bl = *(const u16x8*)(TBl + ((nt * 4 + ds) << 9) + lane * 8);
#pragma unroll
      for (int mt = 0; mt < 2; ++mt) {
        acc[mt][nt] = __builtin_amdgcn_mfma_f32_16x16x32_bf16(asbf(ah[mt][ds]), asbf(bh), acc[mt][nt], 0, 0, 0);
        acc[mt][nt] = __builtin_amdgcn_mfma_f32_16x16x32_bf16(asbf(ah[mt][ds]), asbf(bl), acc[mt][nt], 0, 0, 0);
        acc[mt][nt] = __builtin_amdgcn_mfma_f32_16x16x32_bf16(asbf(al[mt][ds]), asbf(bh), acc[mt][nt], 0, 0, 0);
      }
    }
  }
  __syncthreads();

  ushort_t* OS = (ushort_t*)WoS;
#pragma unroll
  for (int mt = 0; mt < 2; ++mt)
#pragma unroll
    for (int nt = 0; nt < 8; ++nt)
#pragma unroll
      for (int reg = 0; reg < 4; ++reg)
        OS[(w * 32 + mt * 16 + g * 4 + reg) * 136 + nt * 16 + c] = f2b(acc[mt][nt][reg]);
  __syncthreads();

#pragma unroll
  for (int i = 0; i < 8; ++i) {
    int idx = tid + i * 256;
    int nn = idx >> 4, c8 = (idx & 15) * 8;
    *(u16x8*)&WT[(size_t)(n0 + nn) * 4096 + h * 128 + c8] = *(const u16x8*)&OS[nn * 136 + c8];
  }
}

// ---------------- bf16 MFMA GEMM (m97 structure): C = A x BT^T (final Wo GEMM) -------
__global__ __launch_bounds__(256) void gemm_bf16(const ushort_t* __restrict__ A,
                                                 const ushort_t* __restrict__ BT,
                                                 float* __restrict__ C,
                                                 int M, int N, int K, int qlayout)
{
  __shared__ __align__(16) ushort_t As[128 * 64];
  __shared__ __align__(16) ushort_t Bs[128 * 64];
  const int tid = threadIdx.x;
  const int bm = blockIdx.y * 128, bn = blockIdx.x * 128;
  const int lane = tid & 63, w = tid >> 6;
  const int c = lane & 15, g = lane >> 4;
  const int wm = (w >> 1) * 64, wn = (w & 1) * 64;
  f32x4 acc[4][4];
#pragma unroll
  for (int mt = 0; mt < 4; ++mt)
#pragma unroll
    for (int nt = 0; nt < 4; ++nt) acc[mt][nt] = (f32x4){0.f, 0.f, 0.f, 0.f};
  const int srow = tid >> 3;
  const int slot = (tid & 7) ^ (srow & 7);
  for (int k0 = 0; k0 < K; k0 += 64) {
    __syncthreads();
#pragma unroll
    for (int ii = 0; ii < 4; ++ii) {
      gload16(A  + (size_t)(bm + ii * 32 + srow) * K + k0 + slot * 8,
              (char*)As + w * 1024 + ii * 4096);
      gload16(BT + (size_t)(bn + ii * 32 + srow) * K + k0 + slot * 8,
              (char*)Bs + w * 1024 + ii * 4096);
    }
    __syncthreads();
#pragma unroll
    for (int ks = 0; ks < 2; ++ks) {
      bf16x8 av[4], bv[4];
#pragma unroll
      for (int mt = 0; mt < 4; ++mt)
        av[mt] = *(const bf16x8*)((const char*)As + (wm + mt * 16 + c) * 128 +
                                  (((ks * 4 + g) ^ (c & 7)) << 4));
#pragma unroll
      for (int nt = 0; nt < 4; ++nt)
        bv[nt] = *(const bf16x8*)((const char*)Bs + (wn + nt * 16 + c) * 128 +
                                  (((ks * 4 + g) ^ (c & 7)) << 4));
#pragma unroll
      for (int mt = 0; mt < 4; ++mt)
#pragma unroll
        for (int nt = 0; nt < 4; ++nt)
          acc[mt][nt] = __builtin_amdgcn_mfma_f32_16x16x32_bf16(av[mt], bv[nt], acc[mt][nt], 0, 0, 0);
    }
  }
#pragma unroll
  for (int mt = 0; mt < 4; ++mt)
#pragma unroll
    for (int nt = 0; nt < 4; ++nt)
#pragma unroll
      for (int reg = 0; reg < 4; ++reg) {
        int m = bm + wm + mt * 16 + g * 4 + reg;
        int n = bn + wn + nt * 16 + c;
        float v = acc[mt][nt][reg];
        if (qlayout) C[((size_t)(n >> 7) * S_ + m) * 128 + (n & 127)] = v;
        else         C[(size_t)m * N + n] = v;
      }
}

// ---------------- gemm_qkv: fused Wq GEMM (path 0) + Wk/Wv 3-pass GEMM (path 1) ------
// 1024 blocks alternating paths -> both GEMMs co-resident on every CU, each path's
// barrier/vmcnt stalls overlap the other's MFMA. Bodies identical to the two parents.
__global__ __launch_bounds__(256) void gemm_qkv(
    const ushort_t* __restrict__ Ahi, const ushort_t* __restrict__ Alo,
    const ushort_t* __restrict__ WqT,
    const ushort_t* __restrict__ KVh, const ushort_t* __restrict__ KVl,
    float* __restrict__ Cq, float* __restrict__ Ck, float* __restrict__ Cv)
{
  __shared__ __align__(16) char smem[49152];
  const int b = blockIdx.x;         // 0..1023
  const int path = b & 1;           // 0 = q, 1 = kv
  const int idx = b >> 1;           // 0..511
  const int tid = threadIdx.x;
  const int lane = tid & 63, w = tid >> 6;
  const int c = lane & 15, g = lane >> 4;
  const int srow = tid >> 3;
  const int slot = (tid & 7) ^ (srow & 7);
  const int K = DM_;

  if (path == 0) {
    ushort_t* As = (ushort_t*)smem;
    ushort_t* Bs = (ushort_t*)smem + 128 * 64;
    const int bn = (idx & 31) * 128, bm = (idx >> 5) * 128;
    const int wm = (w >> 1) * 64, wn = (w & 1) * 64;
    f32x4 acc[4][4];
#pragma unroll
    for (int mt = 0; mt < 4; ++mt)
#pragma unroll
      for (int nt = 0; nt < 4; ++nt) acc[mt][nt] = (f32x4){0.f, 0.f, 0.f, 0.f};
    for (int k0 = 0; k0 < K; k0 += 64) {
      __syncthreads();
#pragma unroll
      for (int ii = 0; ii < 4; ++ii) {
        gload16(Ahi + (size_t)(bm + ii * 32 + srow) * K + k0 + slot * 8,
                (char*)As + w * 1024 + ii * 4096);
        gload16(WqT + (size_t)(bn + ii * 32 + srow) * K + k0 + slot * 8,
                (char*)Bs + w * 1024 + ii * 4096);
      }
      __syncthreads();
#pragma unroll
      for (int ks = 0; ks < 2; ++ks) {
        bf16x8 av[4], bv[4];
#pragma unroll
        for (int mt = 0; mt < 4; ++mt)
          av[mt] = *(const bf16x8*)((const char*)As + (wm + mt * 16 + c) * 128 +
                                    (((ks * 4 + g) ^ (c & 7)) << 4));
#pragma unroll
        for (int nt = 0; nt < 4; ++nt)
          bv[nt] = *(const bf16x8*)((const char*)Bs + (wn + nt * 16 + c) * 128 +
                                    (((ks * 4 + g) ^ (c & 7)) << 4));
#pragma unroll
        for (int mt = 0; mt < 4; ++mt)
#pragma unroll
          for (int nt = 0; nt < 4; ++nt)
            acc[mt][nt] = __builtin_amdgcn_mfma_f32_16x16x32_bf16(av[mt], bv[nt], acc[mt][nt], 0, 0, 0);
      }
    }
#pragma unroll
    for (int mt = 0; mt < 4; ++mt)
#pragma unroll
      for (int nt = 0; nt < 4; ++nt)
#pragma unroll
        for (int reg = 0; reg < 4; ++reg) {
          int m = bm + wm + mt * 16 + g * 4 + reg;
          int n = bn + wn + nt * 16 + c;
          Cq[((size_t)(n >> 7) * S_ + m) * 128 + (n & 127)] = acc[mt][nt][reg];
        }
  } else {
    ushort_t* Ash = (ushort_t*)smem;
    ushort_t* Asl = Ash + 128 * 64;
    ushort_t* Bsh = Asl + 128 * 64;
    ushort_t* Bsl = Bsh + 64 * 64;
    const int bn = (idx & 31) * 64, bm = (idx >> 5) * 128;
    const int wm = w * 32;
    f32x4 acc[2][4];
#pragma unroll
    for (int mt = 0; mt < 2; ++mt)
#pragma unroll
      for (int nt = 0; nt < 4; ++nt) acc[mt][nt] = (f32x4){0.f, 0.f, 0.f, 0.f};
    for (int k0 = 0; k0 < K; k0 += 64) {
      __syncthreads();
#pragma unroll
      for (int ii = 0; ii < 4; ++ii) {
        const size_t ga = (size_t)(bm + ii * 32 + srow) * K + k0 + slot * 8;
        gload16(Ahi + ga, (char*)Ash + w * 1024 + ii * 4096);
        gload16(Alo + ga, (char*)Asl + w * 1024 + ii * 4096);
      }
#pragma unroll
      for (int ii = 0; ii < 2; ++ii) {
        const size_t gb = (size_t)(bn + ii * 32 + srow) * K + k0 + slot * 8;
        gload16(KVh + gb, (char*)Bsh + w * 1024 + ii * 4096);
        gload16(KVl + gb, (char*)Bsl + w * 1024 + ii * 4096);
      }
      __syncthreads();
#pragma unroll
      for (int ks = 0; ks < 2; ++ks) {
        bf16x8 ah[2], al[2], bh[4], bl[4];
#pragma unroll
        for (int mt = 0; mt < 2; ++mt) {
          int ro = (wm + mt * 16 + c) * 128;
          int so = ((ks * 4 + g) ^ (c & 7)) << 4;
          ah[mt] = *(const bf16x8*)((const char*)Ash + ro + so);
          al[mt] = *(const bf16x8*)((const char*)Asl + ro + so);
        }
#pragma unroll
        for (int nt = 0; nt < 4; ++nt) {
          int ro = (nt * 16 + c) * 128;
          int so = ((ks * 4 + g) ^ (c & 7)) << 4;
          bh[nt] = *(const bf16x8*)((const char*)Bsh + ro + so);
          bl[nt] = *(const bf16x8*)((const char*)Bsl + ro + so);
        }
#pragma unroll
        for (int mt = 0; mt < 2; ++mt)
#pragma unroll
          for (int nt = 0; nt < 4; ++nt) {
            acc[mt][nt] = __builtin_amdgcn_mfma_f32_16x16x32_bf16(ah[mt], bh[nt], acc[mt][nt], 0, 0, 0);
            acc[mt][nt] = __builtin_amdgcn_mfma_f32_16x16x32_bf16(ah[mt], bl[nt], acc[mt][nt], 0, 0, 0);
            acc[mt][nt] = __builtin_amdgcn_mfma_f32_16x16x32_bf16(al[mt], bh[nt], acc[mt][nt], 0, 0, 0);
          }
      }
    }
#pragma unroll
    for (int mt = 0; mt < 2; ++mt)
#pragma unroll
      for (int nt = 0; nt < 4; ++nt)
#pragma unroll
        for (int reg = 0; reg < 4; ++reg) {
          int m = bm + wm + mt * 16 + g * 4 + reg;
          int n = bn + nt * 16 + c;
          float v = acc[mt][nt][reg];
          if (n < 1024) Ck[((size_t)(n >> 7) * S_ + m) * 128 + (n & 127)] = v;
          else          Cv[((size_t)((n - 1024) >> 7) * S_ + m) * 128 + (n & 127)] = v;
        }
  }
}

// ---------------- tpost_all: merged q/k/v post (rope + @T + scale/quant + frag store) --
__global__ __launch_bounds__(256) void tpost_all(
    const float* __restrict__ qsrc, const float* __restrict__ ksrc,
    const float* __restrict__ vsrc,
    const ushort_t* __restrict__ tfH, const ushort_t* __restrict__ tfL,
    const float* __restrict__ cosT, const float* __restrict__ sinT,
    ushort_t* __restrict__ qfrag, ushort_t* __restrict__ kfrag,
    ushort_t* __restrict__ vfrag)
{
  const int b = blockIdx.x;        // 0..3071
  const float* src; const ushort_t *Thi, *Tlo; ushort_t* outp; int mode, blk;
  if (b < 2048)      { src = qsrc; Thi = tfH;             Tlo = tfL;             outp = qfrag; mode = 0; blk = b; }
  else if (b < 2560) { src = ksrc; Thi = tfH + 16384;     Tlo = tfL + 16384;     outp = kfrag; mode = 1; blk = b - 2048; }
  else               { src = vsrc; Thi = tfH + 2 * 16384; Tlo = tfL + 2 * 16384; outp = vfrag; mode = 2; blk = b - 2560; }

  const int tid = threadIdx.x;
  const int w = tid >> 6, lane = tid & 63;
  const int c = lane & 15, g = lane >> 4;

  __shared__ float raw_[32 * 132];
  __shared__ float rop_[32 * 132];
  __shared__ __align__(16) ushort_t vtile[32][136];

#pragma unroll
  for (int i = 0; i < 4; ++i) {
    int idx = tid + i * 256;
    int row = idx >> 5, c4 = (idx & 31) * 4;
    *(float4*)&raw_[row * 132 + c4] =
        *(const float4*)&src[(size_t)(blk * 32 + row) * 128 + c4];
  }
  __syncthreads();

  {
    const int r = tid >> 3, co = (tid & 7) * 16;
    if (mode <= 1) {
      const int s = (blk & 63) * 32 + r;
      const float* ct = cosT + (size_t)s * 64;
      const float* st = sinT + (size_t)s * 64;
#pragma unroll
      for (int j = 0; j < 16; ++j) {
        int cc = co + j, i2 = cc & 63;
        float x = raw_[r * 132 + cc];
        float other = (cc < 64) ? raw_[r * 132 + cc + 64] : raw_[r * 132 + cc - 64];
        rop_[r * 132 + cc] = (cc < 64) ? (x * ct[i2] - other * st[i2])
                                       : (x * ct[i2] + other * st[i2]);
      }
    } else {
#pragma unroll
      for (int j = 0; j < 16; ++j) {
        int cc = co + j;
        rop_[r * 132 + cc] = raw_[r * 132 + cc];
      }
    }
  }
  __syncthreads();

  u16x8 ahu[2][4], alu[2][4];
#pragma unroll
  for (int mt = 0; mt < 2; ++mt)
#pragma unroll
    for (int ds = 0; ds < 4; ++ds) {
      u16x8 th, tl;
#pragma unroll
      for (int j = 0; j < 8; ++j) {
        float x = rop_[(mt * 16 + c) * 132 + ds * 32 + g * 8 + j];
        ushort_t hb = f2b(x);
        th[j] = hb;
        tl[j] = f2b(x - b2f(hb));
      }
      ahu[mt][ds] = th;
      alu[mt][ds] = tl;
    }

  f32x4 acc[2][2];
#pragma unroll
  for (int mt = 0; mt < 2; ++mt)
#pragma unroll
    for (int nl = 0; nl < 2; ++nl) acc[mt][nl] = (f32x4){0.f, 0.f, 0.f, 0.f};
#pragma unroll
  for (int nl = 0; nl < 2; ++nl) {
    const int nt = w * 2 + nl;
    u16x8 bh[4], bl[4];
#pragma unroll
    for (int ds = 0; ds < 4; ++ds) {
      bh[ds] = *(const u16x8*)(Thi + ((nt * 4 + ds) << 9) + lane * 8);
      bl[ds] = *(const u16x8*)(Tlo + ((nt * 4 + ds) << 9) + lane * 8);
    }
#pragma unroll
    for (int mt = 0; mt < 2; ++mt)
#pragma unroll
      for (int ds = 0; ds < 4; ++ds) {
        acc[mt][nl] = __builtin_amdgcn_mfma_f32_16x16x32_bf16(asbf(ahu[mt][ds]), asbf(bh[ds]), acc[mt][nl], 0, 0, 0);
        acc[mt][nl] = __builtin_amdgcn_mfma_f32_16x16x32_bf16(asbf(ahu[mt][ds]), asbf(bl[ds]), acc[mt][nl], 0, 0, 0);
        acc[mt][nl] = __builtin_amdgcn_mfma_f32_16x16x32_bf16(asbf(alu[mt][ds]), asbf(bh[ds]), acc[mt][nl], 0, 0, 0);
      }
  }
  __syncthreads();

#pragma unroll
  for (int mt = 0; mt < 2; ++mt)
#pragma unroll
    for (int nl = 0; nl < 2; ++nl)
#pragma unroll
      for (int reg = 0; reg < 4; ++reg)
        raw_[(mt * 16 + g * 4 + reg) * 132 + (w * 2 + nl) * 16 + c] = acc[mt][nl][reg];
  __syncthreads();

  const int r = tid >> 3, co = (tid & 7) * 16;
  float vals[16];
#pragma unroll
  for (int j = 0; j < 16; ++j) vals[j] = raw_[r * 132 + co + j];

  if (mode == 0) {
#pragma unroll
    for (int j = 0; j < 16; ++j) vals[j] *= 0.08838834764831845f;
  } else {
    float m = 0.0f;
#pragma unroll
    for (int j = 0; j < 16; ++j) m = fmaxf(m, fabsf(vals[j]));
    m = fmaxf(m, __shfl_xor(m, 1));
    m = fmaxf(m, __shfl_xor(m, 2));
    m = fmaxf(m, __shfl_xor(m, 4));
    const float sc = fmaxf(m * (1.0f / 7.0f), 1e-8f);
#pragma unroll
    for (int j = 0; j < 16; ++j) {
      float qv = rintf(vals[j] / sc);
      qv = fminf(7.0f, fmaxf(-7.0f, qv));
      vals[j] = qv * sc;
    }
  }

  if (mode <= 1) {
    const size_t chunkbase = ((size_t)blk << 13) +
                             ((size_t)((r >> 4) * 4 + (co >> 5)) << 10);
    const int lane0 = ((co >> 3) & 3) * 16 + (r & 15);
    const int lane1 = (((co + 8) >> 3) & 3) * 16 + (r & 15);
    u16x8 o0, o1;
#pragma unroll
    for (int j = 0; j < 8; ++j) { o0[j] = f2b(vals[j]); o1[j] = f2b(vals[j + 8]); }
    *(u16x8*)((char*)outp + chunkbase + lane0 * 16) = o0;
    *(u16x8*)((char*)outp + chunkbase + lane1 * 16) = o1;
  } else {
#pragma unroll
    for (int j = 0; j < 16; ++j) vtile[r][co + j] = f2b(vals[j]);
    __syncthreads();
#pragma unroll
    for (int i = 0; i < 2; ++i) {
      int id = tid + i * 256;
      int dt = id >> 6, ln = id & 63;
      int gg = ln >> 4, cc = ln & 15;
      u16x8 o;
#pragma unroll
      for (int j = 0; j < 8; ++j) o[j] = vtile[gg * 8 + j][dt * 16 + cc];
      *(u16x8*)(outp + (((size_t)blk) << 12) + (dt << 9) + ln * 8) = o;
    }
  }
}

// ---------------- MFMA flash attention v6 (round-10 proven body) ----------------
__global__ __launch_bounds__(256) void attn_mfma6(
    const ushort_t* __restrict__ qf_,
    const ushort_t* __restrict__ kf_,
    const ushort_t* __restrict__ vf_,
    ushort_t* __restrict__ o16)
{
  const int lid = blockIdx.x;
  const int xcd = lid & 7;
  const int idx = lid >> 3;
  const int h   = xcd * 4 + (idx & 3);
  const int kb  = idx >> 2;
  const int kvh = xcd;

  const int tid = threadIdx.x;
  const int w    = tid >> 6;
  const int lane = tid & 63;
  const int c = lane & 15, g = lane >> 4;
  const int qt = (w < 2) ? (2 * kb + w) : (60 - 2 * kb + w);

  __shared__ __align__(16) ushort_t Ps[4][2][16][40];

  const float LOG2E = 1.44269504f;
  const float MBIAS = 28.8539008f;    // p = 2^(s*log2e - MBIAS) = e^(s-20)

  const char* qtile = (const char*)qf_ + (((size_t)(h * 64 + qt)) << 13);
  bf16x8 qf[2][4];
#pragma unroll
  for (int mt = 0; mt < 2; ++mt)
#pragma unroll
    for (int ds = 0; ds < 4; ++ds)
      qf[mt][ds] = *(const bf16x8*)(qtile + ((mt * 4 + ds) << 10) + lane * 16);

  bf16x8 ones;
#pragma unroll
  for (int j = 0; j < 8; ++j) ones[j] = (__bf16)1.0f;

  f32x4 oa[2][8];
#pragma unroll
  for (int mt = 0; mt < 2; ++mt)
#pragma unroll
    for (int dt = 0; dt < 8; ++dt) oa[mt][dt] = (f32x4){0.f, 0.f, 0.f, 0.f};
  f32x4 la[2];
  la[0] = (f32x4){0.f, 0.f, 0.f, 0.f};
  la[1] = (f32x4){0.f, 0.f, 0.f, 0.f};

  const char* kbase = (const char*)kf_ + (((size_t)kvh * 64) << 13);
  const char* vbase = (const char*)vf_ + (((size_t)kvh * 64) << 13);

  for (int kt = 0; kt <= qt; ++kt) {
    const char* ktile = kbase + ((size_t)kt << 13);
    const char* vtile = vbase + ((size_t)kt << 13);
    bf16x8 kc[2][4], vc[8];
#pragma unroll
    for (int nt = 0; nt < 2; ++nt)
#pragma unroll
      for (int ds = 0; ds < 4; ++ds)
        kc[nt][ds] = *(const bf16x8*)(ktile + ((nt * 4 + ds) << 10) + lane * 16);
#pragma unroll
    for (int dt = 0; dt < 8; ++dt)
      vc[dt] = *(const bf16x8*)(vtile + (dt << 10) + lane * 16);

    f32x4 sc[2][2];
#pragma unroll
    for (int mt = 0; mt < 2; ++mt)
#pragma unroll
      for (int nt = 0; nt < 2; ++nt) sc[mt][nt] = (f32x4){0.f, 0.f, 0.f, 0.f};
    __builtin_amdgcn_s_setprio(1);
#pragma unroll
    for (int ds = 0; ds < 4; ++ds) {
      sc[0][0] = __builtin_amdgcn_mfma_f32_16x16x32_bf16(qf[0][ds], kc[0][ds], sc[0][0], 0, 0, 0);
      sc[0][1] = __builtin_amdgcn_mfma_f32_16x16x32_bf16(qf[0][ds], kc[1][ds], sc[0][1], 0, 0, 0);
      sc[1][0] = __builtin_amdgcn_mfma_f32_16x16x32_bf16(qf[1][ds], kc[0][ds], sc[1][0], 0, 0, 0);
      sc[1][1] = __builtin_amdgcn_mfma_f32_16x16x32_bf16(qf[1][ds], kc[1][ds], sc[1][1], 0, 0, 0);
    }
    __builtin_amdgcn_s_setprio(0);

#pragma unroll
    for (int mt = 0; mt < 2; ++mt) {
#pragma unroll
      for (int reg = 0; reg < 4; ++reg) {
        float s0 = sc[mt][0][reg], s1 = sc[mt][1][reg];
        if (kt == qt) {
          int qrl = mt * 16 + g * 4 + reg;
          if (c > qrl)      s0 = -INFINITY;
          if (16 + c > qrl) s1 = -INFINITY;
        }
        float p0 = exp2f(s0 * LOG2E - MBIAS);
        float p1 = exp2f(s1 * LOG2E - MBIAS);
        Ps[w][mt][g * 4 + reg][c]      = f2b(p0);
        Ps[w][mt][g * 4 + reg][16 + c] = f2b(p1);
      }
    }

    bf16x8 pa0 = *reinterpret_cast<const bf16x8*>(&Ps[w][0][c][g * 8]);
    bf16x8 pa1 = *reinterpret_cast<const bf16x8*>(&Ps[w][1][c][g * 8]);
    __builtin_amdgcn_s_setprio(1);
#pragma unroll
    for (int dt = 0; dt < 8; ++dt) {
      oa[0][dt] = __builtin_amdgcn_mfma_f32_16x16x32_bf16(pa0, vc[dt], oa[0][dt], 0, 0, 0);
      oa[1][dt] = __builtin_amdgcn_mfma_f32_16x16x32_bf16(pa1, vc[dt], oa[1][dt], 0, 0, 0);
    }
    la[0] = __builtin_amdgcn_mfma_f32_16x16x32_bf16(pa0, ones, la[0], 0, 0, 0);
    la[1] = __builtin_amdgcn_mfma_f32_16x16x32_bf16(pa1, ones, la[1], 0, 0, 0);
    __builtin_amdgcn_s_setprio(0);
  }

#pragma unroll
  for (int mt = 0; mt < 2; ++mt)
#pragma unroll
    for (int reg = 0; reg < 4; ++reg) {
      float li = 1.0f / la[mt][reg];
      int srow = qt * 32 + mt * 16 + g * 4 + reg;
      ushort_t* orow = o16 + (size_t)srow * DM_ + h * 128;
#pragma unroll
      for (int dt = 0; dt < 8; ++dt)
        orow[dt * 16 + c] = f2b(oa[mt][dt][reg] * li);
    }
}

extern "C" void kernel_launch(void* const* d_in, const int* in_sizes, int n_in,
                              void* d_out, int out_size, void* d_ws, size_t ws_size,
                              hipStream_t stream)
{
  (void)in_sizes; (void)n_in; (void)out_size; (void)ws_size;
  const float* hidden = (const float*)d_in[0];
  const int*   pos    = (const int*)d_in[2];
  const float* lnL    = (const float*)d_in[3];
  const float* lnR    = (const float*)d_in[4];
  const float* Wq     = (const float*)d_in[5];
  const float* Wk     = (const float*)d_in[6];
  const float* Wv     = (const float*)d_in[7];
  const float* Wo     = (const float*)d_in[8];
  const float* Tk     = (const float*)d_in[9];
  const float* Tv     = (const float*)d_in[10];
  float* out = (float*)d_out;

  float* ws   = (float*)d_ws;
  float* hbuf = ws;                                    // 32MB region, subdivided below
  float* kbuf = hbuf + (size_t)S_ * DM_;               // 8MB fp32 K pre-quant [kvh][s][d]
  float* vbuf = kbuf + (size_t)S_ * KVH_ * HD_;        // 8MB fp32 V pre-quant [kvh][s][d]
  float* Tkit = vbuf + (size_t)S_ * KVH_ * HD_;        // inv(Tk)^T
  float* TvI  = Tkit + 128 * 128;                      // inv(Tv)
  float* cosT = TvI + 128 * 128;                       // S*64
  float* sinT = cosT + (size_t)S_ * 64;                // S*64
  ushort_t* hb16 = (ushort_t*)(sinT + (size_t)S_ * 64);   // 16MB bf16 (LN hi; later attn out)
  ushort_t* WT   = hb16 + (size_t)S_ * DM_;               // 32MB bf16 (WqT | KV hi+lo | WoT')
  float* nb      = (float*)(WT + (size_t)DM_ * DM_);      // Newton: 6 x 16384 floats
  ushort_t* tfH  = (ushort_t*)(nb + 6 * 16384);           // 4 x 32KB B-frag hi
  ushort_t* tfL  = tfH + 4 * 16384;                       // 4 x 32KB B-frag lo
  ushort_t* RBh  = tfL + 4 * 16384;                       // 8KB each: R/L 64x64 frag packs
  ushort_t* RBl  = RBh + 4096;
  ushort_t* LBh  = RBl + 4096;
  ushort_t* LBl  = LBh + 4096;

  // subdivision of the 32MB hbuf region:
  char* hbytes = (char*)hbuf;
  ushort_t* hlo16 = (ushort_t*)hbytes;                    // [0,16MB)  LN lo (dead after gemm_qkv)
  ushort_t* qfrag = (ushort_t*)hbytes;                    // [0,16MB)  q fragment tiles
  ushort_t* kfrag = (ushort_t*)(hbytes + (16u << 20));    // [16,20MB) k fragment tiles
  ushort_t* vfrag = (ushort_t*)(hbytes + (20u << 20));    // [20,24MB) v fragment tiles

  ushort_t* WTkh = WT;
  ushort_t* WTkl = WT + (size_t)2048 * DM_;
  ushort_t* WqT  = WT + (size_t)2048 * DM_ * 2;           // NOTE: fits? WT is 32MB = 4096*4096*2B
  // WT layout: rows [0,2048) hi | [2048,4096) lo used by KV; WqT needs its own 32MB —
  // reuse: place WqT in the upper half? 4096*4096 ushort = 32MB total. KV hi+lo =
  // 2048*4096*2 = 16MB + 16MB = 32MB. Conflict! Keep WqT in WT rows as before and
  // KV in the same buffer is NOT possible concurrently. Give WqT the vfrag+ region:
  // it must persist only through gemm_qkv, before tpost writes frags. Use a dedicated
  // region after LBl instead (32MB more of workspace).
  ushort_t* WqTbuf = LBl + 4096;                          // 32MB bf16 [4096][4096]

  float* Xk = nb,              *Xv = nb + 16384;
  float* Yk = nb + 2 * 16384,  *Yv = nb + 3 * 16384;
  float* Xk2 = nb + 4 * 16384, *Xv2 = nb + 5 * 16384;

  float* qbuf = out;  // d_out as q scratch [H][S][128] fp32

  // ---- Newton inverse (4 iters): Tkit = inv(Tk)^T, TvI = inv(Tv)
  newton_init<<<dim3(2, 16), 1024, 0, stream>>>(Tk, Tv, Xk, Xv);
  for (int it = 0; it < 4; ++it) {
    nmm<<<dim3(4, 2), 256, 0, stream>>>(Tk, Xk, Yk, 0, Tv, Xv, Yv, 0, 0);
    const int last = (it == 3);
    float* ok = last ? Tkit : Xk2;
    float* ov = last ? TvI  : Xv2;
    nmm<<<dim3(4, 2), 256, 0, stream>>>(Xk, Yk, ok, last ? 1 : 0, Xv, Yv, ov, 0, 1);
    float* t;
    t = Xk; Xk = Xk2; Xk2 = t;
    t = Xv; Xv = Xv2; Xv2 = t;
  }
  prep_all<<<6, 256, 0, stream>>>(Tkit, Tk, Tv, TvI, lnR, lnL,
                                  tfH, tfL, RBh, RBl, LBh, LBl);

  trans_all<<<6144, 256, 0, stream>>>(Wq, Wk, Wv, WqTbuf, WTkh, WTkl);
  lnrope<<<1024, 256, 0, stream>>>(hidden, pos, RBh, RBl, LBh, LBl,
                                   hb16, hlo16, cosT, sinT);

  gemm_qkv<<<1024, 256, 0, stream>>>(hb16, hlo16, WqTbuf, WTkh, WTkl,
                                     qbuf, kbuf, vbuf);

  tpost_all<<<3072, 256, 0, stream>>>(qbuf, kbuf, vbuf, tfH, tfL,
                                      cosT, sinT, qfrag, kfrag, vfrag);

  attn_mfma6<<<dim3(S_ / 128 * H_), 256, 0, stream>>>(qfrag, kfrag, vfrag, hb16);

  wfold3<<<dim3(DM_ / 128, H_), 256, 0, stream>>>(Wo, tfH + 3 * 16384, tfL + 3 * 16384, WT);
  gemm_bf16<<<dim3(DM_ / 128, S_ / 128), 256, 0, stream>>>(hb16, WT, out, S_, DM_, DM_, 0);
}